// Round 9
// baseline (866.348 us; speedup 1.0000x reference)
//
#include <hip/hip_runtime.h>

typedef _Float16 half_t;
typedef _Float16 half8 __attribute__((ext_vector_type(8)));
typedef _Float16 half2_t __attribute__((ext_vector_type(2)));
typedef float f32x16 __attribute__((ext_vector_type(16)));
typedef float f32x4 __attribute__((ext_vector_type(4)));

#define DEVINL __device__ __forceinline__

// ---------- constants ----------
#define INV_S3 0.57735026918962576f   // 1/sqrt(3)
#define INV_S2 0.70710678118654752f   // 1/sqrt(2)
#define C_OLD  0.89442719099991588f   // 1/sqrt(1.25)
#define A_COLD 0.44721359549995794f   // 0.5/sqrt(1.25)
#define SC_ENV 0.05590169943749474f   // (1/sqrt(20)) * (1/4)
#define SC_FS  0.17677669529663688f   // 1/sqrt(32)
#define SC_FV  0.14433756729740643f   // 1/sqrt(48)
#define SC_OUT 0.03608439182435161f   // (1/4)/sqrt(48) — includes layer-1 fold scale
#define SSD 34                         // sS stride (halfs)
#define VPH 146                        // V stride (halfs)

DEVINL float silu_f(float x) { return x / (1.f + __expf(-x)); }

DEVINL float poly_cut(float u) {
    float u2 = u * u, u4 = u2 * u2, u6 = u4 * u2;
    float f = 1.f - 28.f * u6 + 48.f * u6 * u - 21.f * u6 * u2;
    return (u < 1.f) ? f : 0.f;
}

DEVINL float pkh(float a, float b) {
    half2_t h; h[0] = (half_t)a; h[1] = (half_t)b;
    return __builtin_bit_cast(float, h);
}
DEVINL float2 uph(float p) {
    half2_t h = __builtin_bit_cast(half2_t, p);
    return make_float2((float)h[0], (float)h[1]);
}
DEVINL half8 mk8(const float* w) {
    f32x4 v = {w[0], w[1], w[2], w[3]};
    return __builtin_bit_cast(half8, v);
}
DEVINL float ld_pk2(const half_t* p) {
    half2_t h; h[0] = p[0]; h[1] = p[1];
    return __builtin_bit_cast(float, h);
}
// ---- non-temporal loads only (read-once streams). Stores are REGULAR. ----
DEVINL float ntl_f(const float* p) { return __builtin_nontemporal_load(p); }
DEVINL f32x4 ntl_f4(const void* p) {
    return __builtin_nontemporal_load((const f32x4*)p);
}
DEVINL f32x4 ld_f4(const void* p) { return *reinterpret_cast<const f32x4*>(p); }
DEVINL void st_h8(half8 v, half_t* p) { *reinterpret_cast<half8*>(p) = v; }
DEVINL void st_f4(const f32x4& v, float* p) { *reinterpret_cast<f32x4*>(p) = v; }

// =====================================================================
// Edge-column MFMA stage: A = weights [M=features], B = edges (in regs).
// Weight pack: cell(mtile,kblk,m) at halfs[((mtile*KB+kblk)*32+m)*8+j]
// D: lane owns edge col n = lane&31; row f = (r&3) + 8*(r>>2) + 4*(lane>>5).
// =====================================================================
template <int KB>  // K/8
DEVINL f32x16 colstage(const half_t* __restrict__ Wg, const float* B, int mtile,
                       int nl, int q) {
    const half_t* ap = Wg + (((size_t)mtile * KB + q) * 32 + nl) * 8;
    constexpr int H = KB / 2;
    f32x16 acc0;
#pragma unroll
    for (int i = 0; i < 16; ++i) acc0[i] = 0.f;
    if constexpr (H < 2) {
        half8 a = *reinterpret_cast<const half8*>(ap);
        acc0 = __builtin_amdgcn_mfma_f32_32x32x16_f16(a, mk8(B), acc0, 0, 0, 0);
        return acc0;
    } else {
        f32x16 acc1;
#pragma unroll
        for (int i = 0; i < 16; ++i) acc1[i] = 0.f;
#pragma unroll
        for (int h = 0; h + 1 < H; h += 2) {
            half8 a0 = *reinterpret_cast<const half8*>(ap + h * 512);
            half8 a1 = *reinterpret_cast<const half8*>(ap + (h + 1) * 512);
            acc0 = __builtin_amdgcn_mfma_f32_32x32x16_f16(a0, mk8(B + h * 4), acc0, 0, 0, 0);
            acc1 = __builtin_amdgcn_mfma_f32_32x32x16_f16(a1, mk8(B + (h + 1) * 4), acc1, 0, 0, 0);
        }
        if constexpr (H & 1) {
            half8 a = *reinterpret_cast<const half8*>(ap + (H - 1) * 512);
            acc0 = __builtin_amdgcn_mfma_f32_32x32x16_f16(a, mk8(B + (H - 1) * 4), acc0, 0, 0, 0);
        }
        return acc0 + acc1;
    }
}

// ---- explicit register prefetch pipeline for K=128 fold stages ----
struct WFrag { half8 a[8]; };

DEVINL WFrag ldw16(const half_t* __restrict__ Wg, int mtile, int nl, int q) {
    const half_t* ap = Wg + (((size_t)mtile * 16 + q) * 32 + nl) * 8;
    WFrag f;
#pragma unroll
    for (int h = 0; h < 8; ++h)
        f.a[h] = *reinterpret_cast<const half8*>(ap + h * 512);
    return f;
}

DEVINL f32x16 mfma8w(const WFrag& f, const float* B) {
    f32x16 acc0, acc1;
#pragma unroll
    for (int i = 0; i < 16; ++i) { acc0[i] = 0.f; acc1[i] = 0.f; }
#pragma unroll
    for (int h = 0; h < 8; h += 2) {
        acc0 = __builtin_amdgcn_mfma_f32_32x32x16_f16(f.a[h], mk8(B + h * 4), acc0, 0, 0, 0);
        acc1 = __builtin_amdgcn_mfma_f32_32x32x16_f16(f.a[h + 1], mk8(B + (h + 1) * 4), acc1, 0, 0, 0);
    }
    return acc0 + acc1;
}

DEVINL void silu16(f32x16& a) {
#pragma unroll
    for (int i = 0; i < 16; ++i) a[i] = silu_f(a[i]);
}

// D (f32 regs) -> B-frag for next stage: two k-windows of 4 packed floats.
DEVINL void d2b(const f32x16& d, int lane, int q, float* wA, float* wB) {
    float pk[8];
#pragma unroll
    for (int a2 = 0; a2 < 4; ++a2) {
        pk[a2 * 2 + 0] = pkh(d[4 * a2 + 0], d[4 * a2 + 1]);
        pk[a2 * 2 + 1] = pkh(d[4 * a2 + 2], d[4 * a2 + 3]);
    }
#pragma unroll
    for (int t = 0; t < 2; ++t) {
        float k0 = q ? pk[(2 * t + 1) * 2 + 0] : pk[(2 * t) * 2 + 0];
        float k1 = q ? pk[(2 * t + 1) * 2 + 1] : pk[(2 * t) * 2 + 1];
        float s0 = q ? pk[(2 * t) * 2 + 0] : pk[(2 * t + 1) * 2 + 0];
        float s1 = q ? pk[(2 * t) * 2 + 1] : pk[(2 * t + 1) * 2 + 1];
        float r0 = __shfl(s0, lane ^ 32, 64);
        float r1 = __shfl(s1, lane ^ 32, 64);
        float* w = t ? wB : wA;
        w[0] = q ? r0 : k0;
        w[1] = q ? r1 : k1;
        w[2] = q ? k0 : r0;
        w[3] = q ? k1 : r1;
    }
}

// =====================================================================
__global__ __launch_bounds__(256) void k_zero(float* __restrict__ p, int n) {
    int i = blockIdx.x * 256 + threadIdx.x;
    if (i < n) p[i] = 0.f;
}

// =====================================================================
struct PackArgs {
    const float* src[14];
    half_t* dst[14];
    int K[14];
    int N[14];
};

__global__ __launch_bounds__(256) void k_pack(PackArgs pa) {
    int mi = blockIdx.y;
    int K = pa.K[mi], N = pa.N[mi];
    int Npad = (N + 31) & ~31;
    int KB = K >> 3;
    int cells = KB * Npad;
    int cell = blockIdx.x * 256 + threadIdx.x;
    if (cell >= cells) return;
    int nn = cell & 31, r2 = cell >> 5;
    int kblk = r2 % KB, ntile = r2 / KB;
    int n = ntile * 32 + nn;
    const float* W = pa.src[mi];
    half8 v;
#pragma unroll
    for (int j = 0; j < 8; ++j) {
        int k = kblk * 8 + j;
        v[j] = (half_t)((n < N) ? W[k * N + n] : 0.f);
    }
    *reinterpret_cast<half8*>(pa.dst[mi] + (size_t)cell * 8) = v;
}

// =====================================================================
// K1: front. 2 independent waves/block, 32 edges each, no LDS.
// =====================================================================
__global__ __launch_bounds__(128, 4) void k_edge_front(
    const float* __restrict__ g_ea, const float* __restrict__ g_na,
    const float* __restrict__ g_emb, const float* __restrict__ g_eu,
    const int* __restrict__ g_eidx,
    const half_t* __restrict__ b_w2b1, const half_t* __restrict__ b_w2b2,
    const half_t* __restrict__ b_e0w1, const half_t* __restrict__ b_e0w2,
    half_t* __restrict__ g_lat0, float* __restrict__ g_fs, float* __restrict__ g_fv,
    float* __restrict__ raw0, int E) {
    const int lane = threadIdx.x & 63, nl = lane & 31, q = lane >> 5;
    const int g = blockIdx.x * 2 + (threadIdx.x >> 6);
    const int e = g * 32 + nl;
    int ce = g_eidx[e];
    float4 ea = *reinterpret_cast<const float4*>(g_ea + e * 4);
    float cut = poly_cut(g_eu[e]);

    float xw[4];
    if (q == 0) {
        int ne = g_eidx[E + e];
        float4 nc = *reinterpret_cast<const float4*>(g_na + ce * 4);
        float4 nn = *reinterpret_cast<const float4*>(g_na + ne * 4);
        xw[0] = pkh(nc.x, nc.y); xw[1] = pkh(nc.z, nc.w);
        xw[2] = pkh(nn.x, nn.y); xw[3] = pkh(nn.z, nn.w);
    } else {
        f32x4 m0 = ntl_f4(g_emb + e * 8);
        f32x4 m1 = ntl_f4(g_emb + e * 8 + 4);
        xw[0] = pkh(m0[0], m0[1]); xw[1] = pkh(m0[2], m0[3]);
        xw[2] = pkh(m1[0], m1[1]); xw[3] = pkh(m1[2], m1[3]);
    }

    float hB[32], lB[32];
#pragma unroll
    for (int c = 0; c < 4; ++c) {  // w2b1: K=16
        f32x16 d = colstage<2>(b_w2b1, xw, c, nl, q);
        silu16(d);
        d2b(d, lane, q, &hB[8 * c], &hB[8 * c + 4]);
    }
    half_t* gl = g_lat0 + (size_t)g * 4096;
#pragma unroll
    for (int c = 0; c < 4; ++c) {  // w2b2 -> lat = cut*D
        f32x16 d = colstage<16>(b_w2b2, hB, c, nl, q);
#pragma unroll
        for (int i = 0; i < 16; ++i) d[i] *= cut;
        d2b(d, lane, q, &lB[8 * c], &lB[8 * c + 4]);
        st_h8(mk8(&lB[8 * c]), gl + ((4 * c + q) * 32 + nl) * 8);
        st_h8(mk8(&lB[8 * c + 4]), gl + ((4 * c + 2 + q) * 32 + nl) * 8);
    }
#pragma unroll
    for (int c = 0; c < 4; ++c) {  // e0w1
        f32x16 d = colstage<16>(b_e0w1, lB, c, nl, q);
        silu16(d);
        d2b(d, lane, q, &hB[8 * c], &hB[8 * c + 4]);
    }
    {  // e0w2 both mtiles interleaved
        f32x16 d0 = colstage<16>(b_e0w2, hB, 0, nl, q);
        f32x16 d1 = colstage<16>(b_e0w2, hB, 1, nl, q);
#pragma unroll
        for (int r = 0; r < 16; ++r) {
            int f = (r & 3) + 8 * (r >> 2) + 4 * q;
            int u = f >> 1;
            float v0 = d0[r], v1 = d1[r];
            if ((f & 1) == 0) {
                g_fs[e * 16 + u] = v0 * ea.x;
                atomicAdd(&raw0[ce * 64 + u], v1 * ea.x);
            } else {
                g_fv[e * 48 + u * 3 + 0] = v0 * ea.y;
                g_fv[e * 48 + u * 3 + 1] = v0 * ea.z;
                g_fv[e * 48 + u * 3 + 2] = v0 * ea.w;
                atomicAdd(&raw0[ce * 64 + 16 + u * 3 + 0], v1 * ea.y);
                atomicAdd(&raw0[ce * 64 + 16 + u * 3 + 1], v1 * ea.z);
                atomicAdd(&raw0[ce * 64 + 16 + u * 3 + 2], v1 * ea.w);
            }
        }
    }
}

// =====================================================================
// K2: per-node env linear (f32).
// =====================================================================
__global__ __launch_bounds__(256) void k_node_lin(
    const float* __restrict__ raw, const float* __restrict__ wls,
    const float* __restrict__ wlv, float* __restrict__ ls, float* __restrict__ lv,
    int Nn) {
    int gid = blockIdx.x * 256 + threadIdx.x;
    if (gid >= Nn * 16) return;
    int n = gid >> 4, v = gid & 15;
    float as = 0.f, a0 = 0.f, a1 = 0.f, a2 = 0.f;
    const float* rp = raw + n * 64;
#pragma unroll
    for (int u = 0; u < 16; ++u) {
        float w1 = wls[u * 16 + v];
        float w2 = wlv[u * 16 + v];
        as = fmaf(rp[u], w1, as);
        a0 = fmaf(rp[16 + u * 3 + 0], w2, a0);
        a1 = fmaf(rp[16 + u * 3 + 1], w2, a1);
        a2 = fmaf(rp[16 + u * 3 + 2], w2, a2);
    }
    ls[n * 16 + v] = as * SC_ENV;
    lv[n * 48 + v * 3 + 0] = a0 * SC_ENV;
    lv[n * 48 + v * 3 + 1] = a1 * SC_ENV;
    lv[n * 48 + v * 3 + 2] = a2 * SC_ENV;
}

// =====================================================================
// K3a: layer0 LATENT kernel — one wave per 32 edges; sS-only LDS (2.2KB).
// =====================================================================
__global__ __launch_bounds__(64, 2) void k_lat0(
    const float* __restrict__ g_ea, const float* __restrict__ g_eu,
    const int* __restrict__ g_eidx,
    const float* __restrict__ g_fs, const float* __restrict__ g_fv,
    const float* __restrict__ ls0, const float* __restrict__ lv0,
    const half_t* __restrict__ b_lat1w1, const half_t* __restrict__ b_lat1w2,
    const half_t* __restrict__ b_e1w1, const half_t* __restrict__ b_e1w2,
    const half_t* __restrict__ g_lat0, half_t* __restrict__ g_lat1,
    float* __restrict__ raw1, int E) {
    __shared__ half_t sS[32 * SSD];
    const int lane = threadIdx.x, nl = lane & 31, q = lane >> 5;
    const int g = blockIdx.x;
    const int e = g * 32 + nl;
    int ce = g_eidx[e];

#pragma unroll
    for (int mm = 0; mm < 8; ++mm) {
        int m = q * 8 + mm;
        float fs = ntl_f(g_fs + e * 16 + m);
        float fv0 = ntl_f(g_fv + e * 48 + m * 3 + 0);
        float fv1 = ntl_f(g_fv + e * 48 + m * 3 + 1);
        float fv2 = ntl_f(g_fv + e * 48 + m * 3 + 2);
        float es = ls0[ce * 16 + m];
        float ev0 = lv0[ce * 48 + m * 3 + 0];
        float ev1 = lv0[ce * 48 + m * 3 + 1];
        float ev2 = lv0[ce * 48 + m * 3 + 2];
        sS[nl * SSD + 2 * m + 0] = (half_t)(fs * es);
        sS[nl * SSD + 2 * m + 1] =
            (half_t)((fv0 * ev0 + fv1 * ev1 + fv2 * ev2) * INV_S3);
    }

    float lB[40];
    const half_t* gl0 = g_lat0 + (size_t)g * 4096;
#pragma unroll
    for (int h = 0; h < 8; ++h) {
        f32x4 v = ntl_f4(gl0 + ((2 * h + q) * 32 + nl) * 8);
        lB[h * 4 + 0] = v[0]; lB[h * 4 + 1] = v[1];
        lB[h * 4 + 2] = v[2]; lB[h * 4 + 3] = v[3];
    }
    __syncthreads();

#pragma unroll
    for (int j2 = 0; j2 < 4; ++j2) {
        lB[32 + j2] = ld_pk2(sS + nl * SSD + 8 * q + 2 * j2);
        lB[36 + j2] = ld_pk2(sS + nl * SSD + 16 + 8 * q + 2 * j2);
    }

    float hB[32];
    float4 ea = *reinterpret_cast<const float4*>(g_ea + e * 4);
    float cut = poly_cut(g_eu[e]);
#pragma unroll
    for (int c = 0; c < 4; ++c) {  // lat1w1
        f32x16 d = colstage<20>(b_lat1w1, lB, c, nl, q);
        silu16(d);
        d2b(d, lane, q, &hB[8 * c], &hB[8 * c + 4]);
    }
    half_t* gl1 = g_lat1 + (size_t)g * 4096;
    float sc = A_COLD * cut;
#pragma unroll
    for (int c = 0; c < 4; ++c) {  // lat1w2 + combine -> lat'
        f32x16 d = colstage<16>(b_lat1w2, hB, c, nl, q);
#pragma unroll
        for (int i = 0; i < 16; ++i) d[i] *= sc;
        float nw[8];
        d2b(d, lane, q, nw, nw + 4);
#pragma unroll
        for (int p = 0; p < 8; ++p) {
            float2 o = uph(lB[8 * c + p]);
            float2 nn2 = uph(nw[p]);
            lB[8 * c + p] = pkh(C_OLD * o.x + nn2.x, C_OLD * o.y + nn2.y);
        }
        st_h8(mk8(&lB[8 * c]), gl1 + ((4 * c + q) * 32 + nl) * 8);
        st_h8(mk8(&lB[8 * c + 4]), gl1 + ((4 * c + 2 + q) * 32 + nl) * 8);
    }
#pragma unroll
    for (int c = 0; c < 4; ++c) {  // e1w1 (K=128, lat' windows 0..7)
        f32x16 d = colstage<16>(b_e1w1, lB, c, nl, q);
        silu16(d);
        d2b(d, lane, q, &hB[8 * c], &hB[8 * c + 4]);
    }
    {  // e1w2 -> raw1 scatter
        f32x16 d = colstage<16>(b_e1w2, hB, 0, nl, q);
#pragma unroll
        for (int r = 0; r < 16; ++r) {
            int f = (r & 3) + 8 * (r >> 2) + 4 * q;
            int u = f >> 1;
            float val = d[r];
            if ((f & 1) == 0) {
                atomicAdd(&raw1[ce * 64 + u], val * ea.x);
            } else {
                atomicAdd(&raw1[ce * 64 + 16 + u * 3 + 0], val * ea.y);
                atomicAdd(&raw1[ce * 64 + 16 + u * 3 + 1], val * ea.z);
                atomicAdd(&raw1[ce * 64 + 16 + u * 3 + 2], val * ea.w);
            }
        }
    }
}

// =====================================================================
// K3b: layer0 FOLD kernel — 2 fold waves/block (groups 2b, 2b+1) share a
// double-buffered LDS weight stage. Per mtile: issue coalesced global
// loads for mtile c+1 (4 x f32x4 / thread) -> consume mtile c from LDS
// (ds_read_b128 + MFMA + S/V accum) -> ds_write c+1 -> __syncthreads.
// The barrier's vmcnt/lgkm drain makes the handoff race-free (m97 pattern).
// =====================================================================
__global__ __launch_bounds__(128, 2) void k_fold0(
    const int* __restrict__ g_eidx,
    const float* __restrict__ g_fs, const float* __restrict__ g_fv,
    float* __restrict__ gfs2, float* __restrict__ gfv2,
    const float* __restrict__ ls0, const float* __restrict__ lv0,
    const half_t* __restrict__ b_gw1, const half_t* __restrict__ b_gw2,
    const half_t* __restrict__ g_lat0, int E) {
    __shared__ half_t sS2[2][32 * SSD];
    __shared__ half_t Vsh2[2][32 * VPH];
    __shared__ f32x4 Wbuf[2][512];  // 2 x 8KB mtile, 16B-aligned
    const int tid = threadIdx.x;
    const int lane = tid & 63, nl = lane & 31, q = lane >> 5;
    const int wid = tid >> 6;
    const int g = blockIdx.x * 2 + wid;
    const int e = g * 32 + nl;
    int ce = g_eidx[e];
    half_t* sS = sS2[wid];
    half_t* Vsh = Vsh2[wid];

    // stage mtile 0 issue (coalesced; hidden under gather + gw1)
    const f32x4* gsrc = reinterpret_cast<const f32x4*>(b_gw2);
    f32x4 st[4];
#pragma unroll
    for (int k = 0; k < 4; ++k) st[k] = ld_f4(gsrc + k * 128 + tid);

    // gather own group: lane-half covers m = 8q..8q+7
#pragma unroll
    for (int mm = 0; mm < 8; ++mm) {
        int m = q * 8 + mm;
        float fs = ntl_f(g_fs + e * 16 + m);
        float fv0 = ntl_f(g_fv + e * 48 + m * 3 + 0);
        float fv1 = ntl_f(g_fv + e * 48 + m * 3 + 1);
        float fv2 = ntl_f(g_fv + e * 48 + m * 3 + 2);
        float es = ls0[ce * 16 + m];
        float ev0 = lv0[ce * 48 + m * 3 + 0];
        float ev1 = lv0[ce * 48 + m * 3 + 1];
        float ev2 = lv0[ce * 48 + m * 3 + 2];
        sS[nl * SSD + 2 * m + 0] = (half_t)(fs * es);
        sS[nl * SSD + 2 * m + 1] =
            (half_t)((fv0 * ev0 + fv1 * ev1 + fv2 * ev2) * INV_S3);
        half_t* vp = Vsh + nl * VPH;
        vp[m * 3 + 0] = (half_t)(fs * ev0);
        vp[m * 3 + 1] = (half_t)(fs * ev1);
        vp[m * 3 + 2] = (half_t)(fs * ev2);
        vp[(16 + m) * 3 + 0] = (half_t)(fv0 * es);
        vp[(16 + m) * 3 + 1] = (half_t)(fv1 * es);
        vp[(16 + m) * 3 + 2] = (half_t)(fv2 * es);
        vp[(32 + m) * 3 + 0] = (half_t)((fv1 * ev2 - fv2 * ev1) * INV_S2);
        vp[(32 + m) * 3 + 1] = (half_t)((fv2 * ev0 - fv0 * ev2) * INV_S2);
        vp[(32 + m) * 3 + 2] = (half_t)((fv0 * ev1 - fv1 * ev0) * INV_S2);
    }

    float lB[40];
    const half_t* gl0 = g_lat0 + (size_t)g * 4096;
#pragma unroll
    for (int h = 0; h < 8; ++h) {
        f32x4 v = ntl_f4(gl0 + ((2 * h + q) * 32 + nl) * 8);
        lB[h * 4 + 0] = v[0]; lB[h * 4 + 1] = v[1];
        lB[h * 4 + 2] = v[2]; lB[h * 4 + 3] = v[3];
    }
    __syncthreads();  // sS/Vsh visible (own-wave, but also rendezvous)

#pragma unroll
    for (int j2 = 0; j2 < 4; ++j2) {
        lB[32 + j2] = ld_pk2(sS + nl * SSD + 8 * q + 2 * j2);
        lB[36 + j2] = ld_pk2(sS + nl * SSD + 16 + 8 * q + 2 * j2);
    }

    float hB[32];
#pragma unroll
    for (int c = 0; c < 4; ++c) {  // gw1 (direct; hides stage-0 latency)
        f32x16 d = colstage<20>(b_gw1, lB, c, nl, q);
        silu16(d);
        d2b(d, lane, q, &hB[8 * c], &hB[8 * c + 4]);
    }

    // write stage 0, publish
    {
        f32x4* wb = &Wbuf[0][0];
#pragma unroll
        for (int k = 0; k < 4; ++k) wb[k * 128 + tid] = st[k];
    }
    __syncthreads();

    float fsacc[8];
    float fvacc[8][3];
#pragma unroll
    for (int s = 0; s < 8; ++s) {
        fsacc[s] = 0.f;
        fvacc[s][0] = fvacc[s][1] = fvacc[s][2] = 0.f;
    }

    for (int c = 0; c < 40; ++c) {
        const int buf = c & 1;
        // issue stage loads for mtile c+1 (coalesced 16B/lane)
        if (c + 1 < 40) {
#pragma unroll
            for (int k = 0; k < 4; ++k)
                st[k] = ld_f4(gsrc + (size_t)(c + 1) * 512 + k * 128 + tid);
        }
        // consume mtile c from LDS
        f32x16 d;
        {
            WFrag f;
            const half_t* wp = reinterpret_cast<const half_t*>(&Wbuf[buf][0]);
#pragma unroll
            for (int h = 0; h < 8; ++h)
                f.a[h] = *reinterpret_cast<const half8*>(
                    wp + ((q + 2 * h) * 32 + nl) * 8);
            d = mfma8w(f, hB);
        }
        if (c < 16) {
            int pu0 = 2 * c, pu1 = pu0 + 1;
            float S0 = (float)sS[nl * SSD + 2 * (pu0 & 15) + (pu0 >> 4)];
            float S1 = (float)sS[nl * SSD + 2 * (pu1 & 15) + (pu1 >> 4)];
#pragma unroll
            for (int r = 0; r < 16; ++r) {
                int a = r >> 2, bb = r & 3, slot = (a & 1) * 4 + bb;
                fsacc[slot] = fmaf((a < 2) ? S0 : S1, d[r], fsacc[slot]);
            }
        } else {
            int w0i = 2 * c - 32, w1i = w0i + 1;
            const half_t* vp = Vsh + nl * VPH;
            float V00 = (float)vp[w0i * 3], V01 = (float)vp[w0i * 3 + 1], V02 = (float)vp[w0i * 3 + 2];
            float V10 = (float)vp[w1i * 3], V11 = (float)vp[w1i * 3 + 1], V12 = (float)vp[w1i * 3 + 2];
#pragma unroll
            for (int r = 0; r < 16; ++r) {
                int a = r >> 2, bb = r & 3, slot = (a & 1) * 4 + bb;
                float x0 = (a < 2) ? V00 : V10;
                float x1 = (a < 2) ? V01 : V11;
                float x2 = (a < 2) ? V02 : V12;
                fvacc[slot][0] = fmaf(x0, d[r], fvacc[slot][0]);
                fvacc[slot][1] = fmaf(x1, d[r], fvacc[slot][1]);
                fvacc[slot][2] = fmaf(x2, d[r], fvacc[slot][2]);
            }
        }
        __builtin_amdgcn_sched_barrier(0);  // keep ds_write (and vmcnt wait) late
        if (c + 1 < 40) {
            f32x4* wb = &Wbuf[buf ^ 1][0];
#pragma unroll
            for (int k = 0; k < 4; ++k) wb[k * 128 + tid] = st[k];
        }
        __syncthreads();  // publishes c+1; also gates re-use of buf parity
    }

    {   // vectorized writeback: v = (s&3) + 4q + 8*(s>>2)
        float* fp = gfs2 + e * 16 + 4 * q;
        f32x4 flo = {fsacc[0] * SC_FS, fsacc[1] * SC_FS,
                     fsacc[2] * SC_FS, fsacc[3] * SC_FS};
        f32x4 fhi = {fsacc[4] * SC_FS, fsacc[5] * SC_FS,
                     fsacc[6] * SC_FS, fsacc[7] * SC_FS};
        st_f4(flo, fp);
        st_f4(fhi, fp + 8);
        float t[24];
#pragma unroll
        for (int s = 0; s < 4; ++s) {
#pragma unroll
            for (int c3 = 0; c3 < 3; ++c3) {
                t[s * 3 + c3] = fvacc[s][c3] * SC_FV;
                t[12 + s * 3 + c3] = fvacc[4 + s][c3] * SC_FV;
            }
        }
        float* vlo = gfv2 + e * 48 + 12 * q;
        float* vhi = gfv2 + e * 48 + 24 + 12 * q;
#pragma unroll
        for (int i = 0; i < 3; ++i) {
            f32x4 a = {t[4 * i + 0], t[4 * i + 1], t[4 * i + 2], t[4 * i + 3]};
            f32x4 b = {t[12 + 4 * i + 0], t[12 + 4 * i + 1],
                       t[12 + 4 * i + 2], t[12 + 4 * i + 3]};
            st_f4(a, vlo + 4 * i);
            st_f4(b, vhi + 4 * i);
        }
    }
}

// =====================================================================
// K5: layer1 — one wave per 32 edges; pinned-prefetch 24-mtile fold;
// fw/fv combine in registers + shfl; direct g_out store. (unchanged)
// =====================================================================
__global__ __launch_bounds__(64, 2) void k_layer1(
    const int* __restrict__ g_eidx, const float* __restrict__ gfs2,
    const float* __restrict__ gfv2, const float* __restrict__ ls1,
    const float* __restrict__ lv1,
    const half_t* __restrict__ b_flw1, const half_t* __restrict__ b_flw2,
    const half_t* __restrict__ b_gw1, const half_t* __restrict__ b_gw2,
    const half_t* __restrict__ g_lat1, float* __restrict__ g_out, int E) {
    __shared__ half_t sS[32 * SSD];
    __shared__ half_t Vsh[32 * VPH];
    const int lane = threadIdx.x, nl = lane & 31, q = lane >> 5;
    const int g = blockIdx.x;
    const int e = g * 32 + nl;
    int ce = g_eidx[e];

    float lB[40];
    const half_t* gl1 = g_lat1 + (size_t)g * 4096;
#pragma unroll
    for (int h = 0; h < 8; ++h) {
        f32x4 v = ntl_f4(gl1 + ((2 * h + q) * 32 + nl) * 8);
        lB[h * 4 + 0] = v[0]; lB[h * 4 + 1] = v[1];
        lB[h * 4 + 2] = v[2]; lB[h * 4 + 3] = v[3];
    }
#pragma unroll
    for (int mm = 0; mm < 8; ++mm) {
        int m = q * 8 + mm;
        float fs = ntl_f(gfs2 + e * 16 + m);
        float fv0 = ntl_f(gfv2 + e * 48 + m * 3 + 0);
        float fv1 = ntl_f(gfv2 + e * 48 + m * 3 + 1);
        float fv2 = ntl_f(gfv2 + e * 48 + m * 3 + 2);
        float es = ls1[ce * 16 + m];
        float ev0 = lv1[ce * 48 + m * 3 + 0];
        float ev1 = lv1[ce * 48 + m * 3 + 1];
        float ev2 = lv1[ce * 48 + m * 3 + 2];
        float s1 = fs * es;
        float s2 = (fv0 * ev0 + fv1 * ev1 + fv2 * ev2) * INV_S3;
        sS[nl * SSD + 2 * m + 0] = (half_t)s1;
        sS[nl * SSD + 2 * m + 1] = (half_t)s2;
        half_t* vp = Vsh + nl * VPH;
        vp[m * 3 + 0] = (half_t)(fs * ev0);
        vp[m * 3 + 1] = (half_t)(fs * ev1);
        vp[m * 3 + 2] = (half_t)(fs * ev2);
        vp[(16 + m) * 3 + 0] = (half_t)(fv0 * es);
        vp[(16 + m) * 3 + 1] = (half_t)(fv1 * es);
        vp[(16 + m) * 3 + 2] = (half_t)(fv2 * es);
        vp[(32 + m) * 3 + 0] = (half_t)((fv1 * ev2 - fv2 * ev1) * INV_S2);
        vp[(32 + m) * 3 + 1] = (half_t)((fv2 * ev0 - fv0 * ev2) * INV_S2);
        vp[(32 + m) * 3 + 2] = (half_t)((fv0 * ev1 - fv1 * ev0) * INV_S2);
    }
    __syncthreads();

#pragma unroll
    for (int j2 = 0; j2 < 4; ++j2) {
        lB[32 + j2] = ld_pk2(sS + nl * SSD + 8 * q + 2 * j2);
        lB[36 + j2] = ld_pk2(sS + nl * SSD + 16 + 8 * q + 2 * j2);
    }

    float hB[32];
#pragma unroll
    for (int c = 0; c < 4; ++c) {  // flw1
        f32x16 d = colstage<20>(b_flw1, lB, c, nl, q);
        silu16(d);
        d2b(d, lane, q, &hB[8 * c], &hB[8 * c + 4]);
    }
    float fw[8];
    {  // flw2 (N=16)
        f32x16 d = colstage<16>(b_flw2, hB, 0, nl, q);
#pragma unroll
        for (int r = 0; r < 8; ++r) fw[r] = d[r];
    }
#pragma unroll
    for (int c = 0; c < 4; ++c) {  // gw1
        f32x16 d = colstage<20>(b_gw1, lB, c, nl, q);
        silu16(d);
        d2b(d, lane, q, &hB[8 * c], &hB[8 * c + 4]);
    }
    {  // gw2 wv fold: mtiles 16..39 with 2-deep pinned register prefetch
        float fvacc[8][3];
#pragma unroll
        for (int s = 0; s < 8; ++s) fvacc[s][0] = fvacc[s][1] = fvacc[s][2] = 0.f;
        WFrag w0 = ldw16(b_gw2, 16, nl, q);
        WFrag w1 = ldw16(b_gw2, 17, nl, q);
        for (int c = 16; c < 40; ++c) {
            __builtin_amdgcn_sched_barrier(0);
            WFrag wn = w1;
            if (c + 2 < 40) wn = ldw16(b_gw2, c + 2, nl, q);
            __builtin_amdgcn_sched_barrier(0);
            f32x16 d = mfma8w(w0, hB);
            int w0i = 2 * c - 32, w1i = w0i + 1;
            const half_t* vp = Vsh + nl * VPH;
            float V00 = (float)vp[w0i * 3], V01 = (float)vp[w0i * 3 + 1], V02 = (float)vp[w0i * 3 + 2];
            float V10 = (float)vp[w1i * 3], V11 = (float)vp[w1i * 3 + 1], V12 = (float)vp[w1i * 3 + 2];
#pragma unroll
            for (int r = 0; r < 16; ++r) {
                int a = r >> 2, bb = r & 3, slot = (a & 1) * 4 + bb;
                float x0 = (a < 2) ? V00 : V10;
                float x1 = (a < 2) ? V01 : V11;
                float x2 = (a < 2) ? V02 : V12;
                fvacc[slot][0] = fmaf(x0, d[r], fvacc[slot][0]);
                fvacc[slot][1] = fmaf(x1, d[r], fvacc[slot][1]);
                fvacc[slot][2] = fmaf(x2, d[r], fvacc[slot][2]);
            }
            w0 = w1;
            w1 = wn;
        }
        float o0 = 0.f, o1 = 0.f, o2 = 0.f;
#pragma unroll
        for (int s = 0; s < 8; ++s) {
            o0 = fmaf(fw[s], fvacc[s][0], o0);
            o1 = fmaf(fw[s], fvacc[s][1], o1);
            o2 = fmaf(fw[s], fvacc[s][2], o2);
        }
        o0 += __shfl(o0, lane ^ 32, 64);
        o1 += __shfl(o1, lane ^ 32, 64);
        o2 += __shfl(o2, lane ^ 32, 64);
        if (q == 0) {
            g_out[e * 3 + 0] = o0 * SC_OUT;
            g_out[e * 3 + 1] = o1 * SC_OUT;
            g_out[e * 3 + 2] = o2 * SC_OUT;
        }
    }
}

// =====================================================================
extern "C" void kernel_launch(void* const* d_in, const int* in_sizes, int n_in,
                              void* d_out, int out_size, void* d_ws, size_t ws_size,
                              hipStream_t stream) {
    const float* g_ea = (const float*)d_in[0];
    const float* g_na = (const float*)d_in[1];
    const float* g_emb = (const float*)d_in[2];
    const float* g_eu = (const float*)d_in[3];
    const int* g_eidx = (const int*)d_in[4];
    const float* w2b1 = (const float*)d_in[5];
    const float* w2b2 = (const float*)d_in[6];
    const float* lat1w1 = (const float*)d_in[7];
    const float* lat1w2 = (const float*)d_in[8];
    const float* e0w1 = (const float*)d_in[9];
    const float* e0w2 = (const float*)d_in[10];
    const float* e1w1 = (const float*)d_in[11];
    const float* e1w2 = (const float*)d_in[12];
    const float* l2w0w1 = (const float*)d_in[13];
    const float* l2w0w2 = (const float*)d_in[14];
    const float* l2w1w1 = (const float*)d_in[15];
    const float* l2w1w2 = (const float*)d_in[16];
    const float* envws = (const float*)d_in[17];
    const float* envwv = (const float*)d_in[18];
    const float* flw1 = (const float*)d_in[19];
    const float* flw2 = (const float*)d_in[20];
    float* out = (float*)d_out;

    const int E = in_sizes[3];       // 120000
    const int Nn = in_sizes[1] / 4;  // 5000
    const int nblk = E / 32;         // 3750
    const int nblk2 = nblk / 2;      // 1875

    float* p = (float*)d_ws;
    float* gfs = p;  p += (size_t)E * 16;
    float* gfv = p;  p += (size_t)E * 48;
    float* gfs2 = p; p += (size_t)E * 16;
    float* gfv2 = p; p += (size_t)E * 48;
    float* raw0 = p; p += (size_t)Nn * 64;
    float* raw1 = p; p += (size_t)Nn * 64;
    float* ls0 = p;  p += (size_t)Nn * 16;
    float* lv0 = p;  p += (size_t)Nn * 48;
    float* ls1 = p;  p += (size_t)Nn * 16;
    float* lv1 = p;  p += (size_t)Nn * 48;
    half_t* hp = (half_t*)p;
    half_t* lat0h = hp; hp += (size_t)nblk * 4096;
    half_t* lat1h = hp; hp += (size_t)nblk * 4096;

    const int KN[14][2] = {{16, 128}, {128, 128}, {128, 128}, {128, 64},
                           {160, 128}, {128, 128}, {128, 128}, {128, 32},
                           {160, 128}, {128, 1280}, {160, 128}, {128, 1280},
                           {160, 128}, {128, 16}};
    const float* srcs[14] = {w2b1, w2b2, e0w1, e0w2, lat1w1, lat1w2, e1w1, e1w2,
                             l2w0w1, l2w0w2, l2w1w1, l2w1w2, flw1, flw2};
    PackArgs pa;
    half_t* bptr[14];
    for (int i = 0; i < 14; ++i) {
        int K = KN[i][0], N = KN[i][1];
        int Npad = (N + 31) & ~31;
        bptr[i] = hp;
        hp += (size_t)K * Npad;
        pa.src[i] = srcs[i];
        pa.dst[i] = bptr[i];
        pa.K[i] = K;
        pa.N[i] = N;
    }

    k_pack<<<dim3(80, 14), 256, 0, stream>>>(pa);

    const int nzero = Nn * 128;  // raw0 + raw1 contiguous
    k_zero<<<(nzero + 255) / 256, 256, 0, stream>>>(raw0, nzero);

    const int nb2 = (Nn * 16 + 255) / 256;

    k_edge_front<<<nblk2, 128, 0, stream>>>(g_ea, g_na, g_emb, g_eu, g_eidx,
                                            bptr[0], bptr[1], bptr[2], bptr[3],
                                            lat0h, gfs, gfv, raw0, E);
    k_node_lin<<<nb2, 256, 0, stream>>>(raw0, envws, envwv, ls0, lv0, Nn);
    k_fold0<<<nblk2, 128, 0, stream>>>(g_eidx, gfs, gfv, gfs2, gfv2, ls0, lv0,
                                       bptr[8], bptr[9], lat0h, E);
    k_lat0<<<nblk, 64, 0, stream>>>(g_ea, g_eu, g_eidx, gfs, gfv, ls0, lv0,
                                    bptr[4], bptr[5], bptr[6], bptr[7],
                                    lat0h, lat1h, raw1, E);
    k_node_lin<<<nb2, 256, 0, stream>>>(raw1, envws + 256, envwv + 256, ls1, lv1, Nn);
    k_layer1<<<nblk, 64, 0, stream>>>(g_eidx, gfs2, gfv2, ls1, lv1,
                                      bptr[12], bptr[13], bptr[10], bptr[11],
                                      lat1h, out, E);
}

// Round 10
// 856.995 us; speedup vs baseline: 1.0109x; 1.0109x over previous
//
#include <hip/hip_runtime.h>

typedef _Float16 half_t;
typedef _Float16 half8 __attribute__((ext_vector_type(8)));
typedef _Float16 half2_t __attribute__((ext_vector_type(2)));
typedef float f32x16 __attribute__((ext_vector_type(16)));
typedef float f32x4 __attribute__((ext_vector_type(4)));

#define DEVINL __device__ __forceinline__

// ---------- constants ----------
#define INV_S3 0.57735026918962576f   // 1/sqrt(3)
#define INV_S2 0.70710678118654752f   // 1/sqrt(2)
#define C_OLD  0.89442719099991588f   // 1/sqrt(1.25)
#define A_COLD 0.44721359549995794f   // 0.5/sqrt(1.25)
#define SC_ENV 0.05590169943749474f   // (1/sqrt(20)) * (1/4)
#define SC_FS  0.17677669529663688f   // 1/sqrt(32)
#define SC_FV  0.14433756729740643f   // 1/sqrt(48)
#define SC_OUT 0.03608439182435161f   // (1/4)/sqrt(48) — includes layer-1 fold scale
#define SSD 34                         // sS stride (halfs)
#define VPH 146                        // V stride (halfs)

DEVINL float silu_f(float x) { return x / (1.f + __expf(-x)); }

DEVINL float poly_cut(float u) {
    float u2 = u * u, u4 = u2 * u2, u6 = u4 * u2;
    float f = 1.f - 28.f * u6 + 48.f * u6 * u - 21.f * u6 * u2;
    return (u < 1.f) ? f : 0.f;
}

DEVINL float pkh(float a, float b) {
    half2_t h; h[0] = (half_t)a; h[1] = (half_t)b;
    return __builtin_bit_cast(float, h);
}
DEVINL float2 uph(float p) {
    half2_t h = __builtin_bit_cast(half2_t, p);
    return make_float2((float)h[0], (float)h[1]);
}
DEVINL half8 mk8(const float* w) {
    f32x4 v = {w[0], w[1], w[2], w[3]};
    return __builtin_bit_cast(half8, v);
}
DEVINL float ld_pk2(const half_t* p) {
    half2_t h; h[0] = p[0]; h[1] = p[1];
    return __builtin_bit_cast(float, h);
}
// ---- non-temporal loads only (read-once streams). Stores are REGULAR. ----
DEVINL float ntl_f(const float* p) { return __builtin_nontemporal_load(p); }
DEVINL f32x4 ntl_f4(const void* p) {
    return __builtin_nontemporal_load((const f32x4*)p);
}
DEVINL f32x4 ld_f4(const void* p) { return *reinterpret_cast<const f32x4*>(p); }
DEVINL void st_h8(half8 v, half_t* p) { *reinterpret_cast<half8*>(p) = v; }
DEVINL void st_f4(const f32x4& v, float* p) { *reinterpret_cast<f32x4*>(p) = v; }

// =====================================================================
// Edge-column MFMA stage: A = weights [M=features], B = edges (in regs).
// Weight pack: cell(mtile,kblk,m) at halfs[((mtile*KB+kblk)*32+m)*8+j]
// D: lane owns edge col n = lane&31; row f = (r&3) + 8*(r>>2) + 4*(lane>>5).
// =====================================================================
template <int KB>  // K/8
DEVINL f32x16 colstage(const half_t* __restrict__ Wg, const float* B, int mtile,
                       int nl, int q) {
    const half_t* ap = Wg + (((size_t)mtile * KB + q) * 32 + nl) * 8;
    constexpr int H = KB / 2;
    f32x16 acc0;
#pragma unroll
    for (int i = 0; i < 16; ++i) acc0[i] = 0.f;
    if constexpr (H < 2) {
        half8 a = *reinterpret_cast<const half8*>(ap);
        acc0 = __builtin_amdgcn_mfma_f32_32x32x16_f16(a, mk8(B), acc0, 0, 0, 0);
        return acc0;
    } else {
        f32x16 acc1;
#pragma unroll
        for (int i = 0; i < 16; ++i) acc1[i] = 0.f;
#pragma unroll
        for (int h = 0; h + 1 < H; h += 2) {
            half8 a0 = *reinterpret_cast<const half8*>(ap + h * 512);
            half8 a1 = *reinterpret_cast<const half8*>(ap + (h + 1) * 512);
            acc0 = __builtin_amdgcn_mfma_f32_32x32x16_f16(a0, mk8(B + h * 4), acc0, 0, 0, 0);
            acc1 = __builtin_amdgcn_mfma_f32_32x32x16_f16(a1, mk8(B + (h + 1) * 4), acc1, 0, 0, 0);
        }
        if constexpr (H & 1) {
            half8 a = *reinterpret_cast<const half8*>(ap + (H - 1) * 512);
            acc0 = __builtin_amdgcn_mfma_f32_32x32x16_f16(a, mk8(B + (H - 1) * 4), acc0, 0, 0, 0);
        }
        return acc0 + acc1;
    }
}

// LDS variant: chunk holds ONE mtile; same cell layout with mtile=0.
template <int KB>
DEVINL f32x16 colstage_lds(const half_t* W, const float* B, int nl, int q) {
    const half_t* ap = W + (q * 32 + nl) * 8;
    constexpr int H = KB / 2;
    f32x16 acc0, acc1;
#pragma unroll
    for (int i = 0; i < 16; ++i) { acc0[i] = 0.f; acc1[i] = 0.f; }
#pragma unroll
    for (int h = 0; h + 1 < H; h += 2) {
        half8 a0 = *reinterpret_cast<const half8*>(ap + h * 512);
        half8 a1 = *reinterpret_cast<const half8*>(ap + (h + 1) * 512);
        acc0 = __builtin_amdgcn_mfma_f32_32x32x16_f16(a0, mk8(B + h * 4), acc0, 0, 0, 0);
        acc1 = __builtin_amdgcn_mfma_f32_32x32x16_f16(a1, mk8(B + (h + 1) * 4), acc1, 0, 0, 0);
    }
    if constexpr (H & 1) {
        half8 a = *reinterpret_cast<const half8*>(ap + (H - 1) * 512);
        acc0 = __builtin_amdgcn_mfma_f32_32x32x16_f16(a, mk8(B + (H - 1) * 4), acc0, 0, 0, 0);
    }
    return acc0 + acc1;
}

// ---- explicit register prefetch pipeline for K=128 fold stages ----
struct WFrag { half8 a[8]; };

DEVINL f32x16 mfma8w(const WFrag& f, const float* B) {
    f32x16 acc0, acc1;
#pragma unroll
    for (int i = 0; i < 16; ++i) { acc0[i] = 0.f; acc1[i] = 0.f; }
#pragma unroll
    for (int h = 0; h < 8; h += 2) {
        acc0 = __builtin_amdgcn_mfma_f32_32x32x16_f16(f.a[h], mk8(B + h * 4), acc0, 0, 0, 0);
        acc1 = __builtin_amdgcn_mfma_f32_32x32x16_f16(f.a[h + 1], mk8(B + (h + 1) * 4), acc1, 0, 0, 0);
    }
    return acc0 + acc1;
}

DEVINL void silu16(f32x16& a) {
#pragma unroll
    for (int i = 0; i < 16; ++i) a[i] = silu_f(a[i]);
}

// D (f32 regs) -> B-frag for next stage: two k-windows of 4 packed floats.
DEVINL void d2b(const f32x16& d, int lane, int q, float* wA, float* wB) {
    float pk[8];
#pragma unroll
    for (int a2 = 0; a2 < 4; ++a2) {
        pk[a2 * 2 + 0] = pkh(d[4 * a2 + 0], d[4 * a2 + 1]);
        pk[a2 * 2 + 1] = pkh(d[4 * a2 + 2], d[4 * a2 + 3]);
    }
#pragma unroll
    for (int t = 0; t < 2; ++t) {
        float k0 = q ? pk[(2 * t + 1) * 2 + 0] : pk[(2 * t) * 2 + 0];
        float k1 = q ? pk[(2 * t + 1) * 2 + 1] : pk[(2 * t) * 2 + 1];
        float s0 = q ? pk[(2 * t) * 2 + 0] : pk[(2 * t + 1) * 2 + 0];
        float s1 = q ? pk[(2 * t) * 2 + 1] : pk[(2 * t + 1) * 2 + 1];
        float r0 = __shfl(s0, lane ^ 32, 64);
        float r1 = __shfl(s1, lane ^ 32, 64);
        float* w = t ? wB : wA;
        w[0] = q ? r0 : k0;
        w[1] = q ? r1 : k1;
        w[2] = q ? k0 : r0;
        w[3] = q ? k1 : r1;
    }
}

// ---- chunk stage helpers (128 threads cooperatively move one mtile) ----
DEVINL void ld5(const f32x4* src, f32x4* st, int tid) {
#pragma unroll
    for (int k = 0; k < 5; ++k) st[k] = ld_f4(src + k * 128 + tid);
}
DEVINL void ld4(const f32x4* src, f32x4* st, int tid) {
#pragma unroll
    for (int k = 0; k < 4; ++k) st[k] = ld_f4(src + k * 128 + tid);
}
DEVINL void wr5(f32x4* dst, const f32x4* st, int tid) {
#pragma unroll
    for (int k = 0; k < 5; ++k) dst[k * 128 + tid] = st[k];
}
DEVINL void wr4(f32x4* dst, const f32x4* st, int tid) {
#pragma unroll
    for (int k = 0; k < 4; ++k) dst[k * 128 + tid] = st[k];
}

// =====================================================================
__global__ __launch_bounds__(256) void k_zero(float* __restrict__ p, int n) {
    int i = blockIdx.x * 256 + threadIdx.x;
    if (i < n) p[i] = 0.f;
}

// =====================================================================
struct PackArgs {
    const float* src[14];
    half_t* dst[14];
    int K[14];
    int N[14];
};

__global__ __launch_bounds__(256) void k_pack(PackArgs pa) {
    int mi = blockIdx.y;
    int K = pa.K[mi], N = pa.N[mi];
    int Npad = (N + 31) & ~31;
    int KB = K >> 3;
    int cells = KB * Npad;
    int cell = blockIdx.x * 256 + threadIdx.x;
    if (cell >= cells) return;
    int nn = cell & 31, r2 = cell >> 5;
    int kblk = r2 % KB, ntile = r2 / KB;
    int n = ntile * 32 + nn;
    const float* W = pa.src[mi];
    half8 v;
#pragma unroll
    for (int j = 0; j < 8; ++j) {
        int k = kblk * 8 + j;
        v[j] = (half_t)((n < N) ? W[k * N + n] : 0.f);
    }
    *reinterpret_cast<half8*>(pa.dst[mi] + (size_t)cell * 8) = v;
}

// =====================================================================
// K1: front. 2 independent waves/block, 32 edges each, no LDS.
// =====================================================================
__global__ __launch_bounds__(128, 4) void k_edge_front(
    const float* __restrict__ g_ea, const float* __restrict__ g_na,
    const float* __restrict__ g_emb, const float* __restrict__ g_eu,
    const int* __restrict__ g_eidx,
    const half_t* __restrict__ b_w2b1, const half_t* __restrict__ b_w2b2,
    const half_t* __restrict__ b_e0w1, const half_t* __restrict__ b_e0w2,
    half_t* __restrict__ g_lat0, float* __restrict__ g_fs, float* __restrict__ g_fv,
    float* __restrict__ raw0, int E) {
    const int lane = threadIdx.x & 63, nl = lane & 31, q = lane >> 5;
    const int g = blockIdx.x * 2 + (threadIdx.x >> 6);
    const int e = g * 32 + nl;
    int ce = g_eidx[e];
    float4 ea = *reinterpret_cast<const float4*>(g_ea + e * 4);
    float cut = poly_cut(g_eu[e]);

    float xw[4];
    if (q == 0) {
        int ne = g_eidx[E + e];
        float4 nc = *reinterpret_cast<const float4*>(g_na + ce * 4);
        float4 nn = *reinterpret_cast<const float4*>(g_na + ne * 4);
        xw[0] = pkh(nc.x, nc.y); xw[1] = pkh(nc.z, nc.w);
        xw[2] = pkh(nn.x, nn.y); xw[3] = pkh(nn.z, nn.w);
    } else {
        f32x4 m0 = ntl_f4(g_emb + e * 8);
        f32x4 m1 = ntl_f4(g_emb + e * 8 + 4);
        xw[0] = pkh(m0[0], m0[1]); xw[1] = pkh(m0[2], m0[3]);
        xw[2] = pkh(m1[0], m1[1]); xw[3] = pkh(m1[2], m1[3]);
    }

    float hB[32], lB[32];
#pragma unroll
    for (int c = 0; c < 4; ++c) {  // w2b1: K=16
        f32x16 d = colstage<2>(b_w2b1, xw, c, nl, q);
        silu16(d);
        d2b(d, lane, q, &hB[8 * c], &hB[8 * c + 4]);
    }
    half_t* gl = g_lat0 + (size_t)g * 4096;
#pragma unroll
    for (int c = 0; c < 4; ++c) {  // w2b2 -> lat = cut*D
        f32x16 d = colstage<16>(b_w2b2, hB, c, nl, q);
#pragma unroll
        for (int i = 0; i < 16; ++i) d[i] *= cut;
        d2b(d, lane, q, &lB[8 * c], &lB[8 * c + 4]);
        st_h8(mk8(&lB[8 * c]), gl + ((4 * c + q) * 32 + nl) * 8);
        st_h8(mk8(&lB[8 * c + 4]), gl + ((4 * c + 2 + q) * 32 + nl) * 8);
    }
#pragma unroll
    for (int c = 0; c < 4; ++c) {  // e0w1
        f32x16 d = colstage<16>(b_e0w1, lB, c, nl, q);
        silu16(d);
        d2b(d, lane, q, &hB[8 * c], &hB[8 * c + 4]);
    }
    {  // e0w2 both mtiles interleaved
        f32x16 d0 = colstage<16>(b_e0w2, hB, 0, nl, q);
        f32x16 d1 = colstage<16>(b_e0w2, hB, 1, nl, q);
#pragma unroll
        for (int r = 0; r < 16; ++r) {
            int f = (r & 3) + 8 * (r >> 2) + 4 * q;
            int u = f >> 1;
            float v0 = d0[r], v1 = d1[r];
            if ((f & 1) == 0) {
                g_fs[e * 16 + u] = v0 * ea.x;
                atomicAdd(&raw0[ce * 64 + u], v1 * ea.x);
            } else {
                g_fv[e * 48 + u * 3 + 0] = v0 * ea.y;
                g_fv[e * 48 + u * 3 + 1] = v0 * ea.z;
                g_fv[e * 48 + u * 3 + 2] = v0 * ea.w;
                atomicAdd(&raw0[ce * 64 + 16 + u * 3 + 0], v1 * ea.y);
                atomicAdd(&raw0[ce * 64 + 16 + u * 3 + 1], v1 * ea.z);
                atomicAdd(&raw0[ce * 64 + 16 + u * 3 + 2], v1 * ea.w);
            }
        }
    }
}

// =====================================================================
// K2: per-node env linear (f32).
// =====================================================================
__global__ __launch_bounds__(256) void k_node_lin(
    const float* __restrict__ raw, const float* __restrict__ wls,
    const float* __restrict__ wlv, float* __restrict__ ls, float* __restrict__ lv,
    int Nn) {
    int gid = blockIdx.x * 256 + threadIdx.x;
    if (gid >= Nn * 16) return;
    int n = gid >> 4, v = gid & 15;
    float as = 0.f, a0 = 0.f, a1 = 0.f, a2 = 0.f;
    const float* rp = raw + n * 64;
#pragma unroll
    for (int u = 0; u < 16; ++u) {
        float w1 = wls[u * 16 + v];
        float w2 = wlv[u * 16 + v];
        as = fmaf(rp[u], w1, as);
        a0 = fmaf(rp[16 + u * 3 + 0], w2, a0);
        a1 = fmaf(rp[16 + u * 3 + 1], w2, a1);
        a2 = fmaf(rp[16 + u * 3 + 2], w2, a2);
    }
    ls[n * 16 + v] = as * SC_ENV;
    lv[n * 48 + v * 3 + 0] = a0 * SC_ENV;
    lv[n * 48 + v * 3 + 1] = a1 * SC_ENV;
    lv[n * 48 + v * 3 + 2] = a2 * SC_ENV;
}

// =====================================================================
// K3a: layer0 LATENT kernel v2 — 2 waves/block (groups 2b,2b+1) share a
// double-buffered LDS weight stage streaming lat1w1→lat1w2→e1w1→e1w2
// with cross-boundary bridging (no pipeline bubbles).
// chunk i lives in Wbuf[i&1]; barrier at end of each iteration retires
// all reads of chunk i before chunk i+2 overwrites that buffer.
// =====================================================================
__global__ __launch_bounds__(128, 2) void k_lat0(
    const float* __restrict__ g_ea, const float* __restrict__ g_eu,
    const int* __restrict__ g_eidx,
    const float* __restrict__ g_fs, const float* __restrict__ g_fv,
    const float* __restrict__ ls0, const float* __restrict__ lv0,
    const half_t* __restrict__ b_lat1w1, const half_t* __restrict__ b_lat1w2,
    const half_t* __restrict__ b_e1w1, const half_t* __restrict__ b_e1w2,
    const half_t* __restrict__ g_lat0, half_t* __restrict__ g_lat1,
    float* __restrict__ raw1, int E) {
    __shared__ half_t sS2[2][32 * SSD];
    __shared__ f32x4 Wbuf[2][640];  // 2 x 10KB (KB=20 chunk max)
    const int tid = threadIdx.x;
    const int lane = tid & 63, nl = lane & 31, q = lane >> 5;
    const int wid = tid >> 6;
    const int g = blockIdx.x * 2 + wid;
    const int e = g * 32 + nl;
    int ce = g_eidx[e];
    half_t* sS = sS2[wid];

    const f32x4* w11 = reinterpret_cast<const f32x4*>(b_lat1w1);  // 4 x 640
    const f32x4* w12 = reinterpret_cast<const f32x4*>(b_lat1w2);  // 4 x 512
    const f32x4* w21 = reinterpret_cast<const f32x4*>(b_e1w1);    // 4 x 512
    const f32x4* w22 = reinterpret_cast<const f32x4*>(b_e1w2);    // 1 x 512

    f32x4 st[5];
    ld5(w11, st, tid);  // chunk 0 in flight, hidden under gather

    // per-wave gather (own group): sS only
#pragma unroll
    for (int mm = 0; mm < 8; ++mm) {
        int m = q * 8 + mm;
        float fs = ntl_f(g_fs + e * 16 + m);
        float fv0 = ntl_f(g_fv + e * 48 + m * 3 + 0);
        float fv1 = ntl_f(g_fv + e * 48 + m * 3 + 1);
        float fv2 = ntl_f(g_fv + e * 48 + m * 3 + 2);
        float es = ls0[ce * 16 + m];
        float ev0 = lv0[ce * 48 + m * 3 + 0];
        float ev1 = lv0[ce * 48 + m * 3 + 1];
        float ev2 = lv0[ce * 48 + m * 3 + 2];
        sS[nl * SSD + 2 * m + 0] = (half_t)(fs * es);
        sS[nl * SSD + 2 * m + 1] =
            (half_t)((fv0 * ev0 + fv1 * ev1 + fv2 * ev2) * INV_S3);
    }

    float lB[40];
    const half_t* gl0 = g_lat0 + (size_t)g * 4096;
#pragma unroll
    for (int h = 0; h < 8; ++h) {
        f32x4 v = ntl_f4(gl0 + ((2 * h + q) * 32 + nl) * 8);
        lB[h * 4 + 0] = v[0]; lB[h * 4 + 1] = v[1];
        lB[h * 4 + 2] = v[2]; lB[h * 4 + 3] = v[3];
    }
    float4 ea = *reinterpret_cast<const float4*>(g_ea + e * 4);
    float cut = poly_cut(g_eu[e]);

    wr5(&Wbuf[0][0], st, tid);
    __syncthreads();  // publishes chunk 0

#pragma unroll
    for (int j2 = 0; j2 < 4; ++j2) {
        lB[32 + j2] = ld_pk2(sS + nl * SSD + 8 * q + 2 * j2);
        lB[36 + j2] = ld_pk2(sS + nl * SSD + 16 + 8 * q + 2 * j2);
    }

    float hB[32];
    // stage A: lat1w1 (KB=20), chunks idx 0..3
#pragma unroll
    for (int c = 0; c < 4; ++c) {
        if (c < 3) ld5(w11 + (size_t)(c + 1) * 640, st, tid);
        else       ld4(w12, st, tid);  // bridge -> lat1w2 chunk 0 (idx 4)
        f32x16 d = colstage_lds<20>(
            reinterpret_cast<const half_t*>(&Wbuf[c & 1][0]), lB, nl, q);
        silu16(d);
        d2b(d, lane, q, &hB[8 * c], &hB[8 * c + 4]);
        __builtin_amdgcn_sched_barrier(0);
        if (c < 3) wr5(&Wbuf[(c + 1) & 1][0], st, tid);
        else       wr4(&Wbuf[(c + 1) & 1][0], st, tid);
        __syncthreads();
    }
    // stage B: lat1w2 (KB=16), chunks idx 4..7 (parity (4+c)&1 == c&1)
    half_t* gl1 = g_lat1 + (size_t)g * 4096;
    float sc = A_COLD * cut;
#pragma unroll
    for (int c = 0; c < 4; ++c) {
        if (c < 3) ld4(w12 + (size_t)(c + 1) * 512, st, tid);
        else       ld4(w21, st, tid);  // bridge -> e1w1 chunk 0 (idx 8)
        f32x16 d = colstage_lds<16>(
            reinterpret_cast<const half_t*>(&Wbuf[c & 1][0]), hB, nl, q);
#pragma unroll
        for (int i = 0; i < 16; ++i) d[i] *= sc;
        float nw[8];
        d2b(d, lane, q, nw, nw + 4);
#pragma unroll
        for (int p = 0; p < 8; ++p) {
            float2 o = uph(lB[8 * c + p]);
            float2 nn2 = uph(nw[p]);
            lB[8 * c + p] = pkh(C_OLD * o.x + nn2.x, C_OLD * o.y + nn2.y);
        }
        st_h8(mk8(&lB[8 * c]), gl1 + ((4 * c + q) * 32 + nl) * 8);
        st_h8(mk8(&lB[8 * c + 4]), gl1 + ((4 * c + 2 + q) * 32 + nl) * 8);
        __builtin_amdgcn_sched_barrier(0);
        wr4(&Wbuf[(c + 1) & 1][0], st, tid);
        __syncthreads();
    }
    // stage C: e1w1 (KB=16), chunks idx 8..11 (parity == c&1)
#pragma unroll
    for (int c = 0; c < 4; ++c) {
        if (c == 3) ld4(w22, st, tid);  // bridge -> e1w2 (idx 12)
        f32x16 d = colstage_lds<16>(
            reinterpret_cast<const half_t*>(&Wbuf[c & 1][0]), lB, nl, q);
        silu16(d);
        d2b(d, lane, q, &hB[8 * c], &hB[8 * c + 4]);
        if (c < 3) ld4(w21 + (size_t)(c + 1) * 512, st, tid);
        __builtin_amdgcn_sched_barrier(0);
        wr4(&Wbuf[(c + 1) & 1][0], st, tid);
        __syncthreads();
    }
    // stage D: e1w2 (idx 12, parity 0) -> raw1 scatter
    {
        f32x16 d = colstage_lds<16>(
            reinterpret_cast<const half_t*>(&Wbuf[0][0]), hB, nl, q);
#pragma unroll
        for (int r = 0; r < 16; ++r) {
            int f = (r & 3) + 8 * (r >> 2) + 4 * q;
            int u = f >> 1;
            float val = d[r];
            if ((f & 1) == 0) {
                atomicAdd(&raw1[ce * 64 + u], val * ea.x);
            } else {
                atomicAdd(&raw1[ce * 64 + 16 + u * 3 + 0], val * ea.y);
                atomicAdd(&raw1[ce * 64 + 16 + u * 3 + 1], val * ea.z);
                atomicAdd(&raw1[ce * 64 + 16 + u * 3 + 2], val * ea.w);
            }
        }
    }
}

// =====================================================================
// K3b: layer0 FOLD kernel — unchanged from round 9 (proven ~96us).
// =====================================================================
__global__ __launch_bounds__(128, 2) void k_fold0(
    const int* __restrict__ g_eidx,
    const float* __restrict__ g_fs, const float* __restrict__ g_fv,
    float* __restrict__ gfs2, float* __restrict__ gfv2,
    const float* __restrict__ ls0, const float* __restrict__ lv0,
    const half_t* __restrict__ b_gw1, const half_t* __restrict__ b_gw2,
    const half_t* __restrict__ g_lat0, int E) {
    __shared__ half_t sS2[2][32 * SSD];
    __shared__ half_t Vsh2[2][32 * VPH];
    __shared__ f32x4 Wbuf[2][512];  // 2 x 8KB mtile
    const int tid = threadIdx.x;
    const int lane = tid & 63, nl = lane & 31, q = lane >> 5;
    const int wid = tid >> 6;
    const int g = blockIdx.x * 2 + wid;
    const int e = g * 32 + nl;
    int ce = g_eidx[e];
    half_t* sS = sS2[wid];
    half_t* Vsh = Vsh2[wid];

    const f32x4* gsrc = reinterpret_cast<const f32x4*>(b_gw2);
    f32x4 st[4];
#pragma unroll
    for (int k = 0; k < 4; ++k) st[k] = ld_f4(gsrc + k * 128 + tid);

#pragma unroll
    for (int mm = 0; mm < 8; ++mm) {
        int m = q * 8 + mm;
        float fs = ntl_f(g_fs + e * 16 + m);
        float fv0 = ntl_f(g_fv + e * 48 + m * 3 + 0);
        float fv1 = ntl_f(g_fv + e * 48 + m * 3 + 1);
        float fv2 = ntl_f(g_fv + e * 48 + m * 3 + 2);
        float es = ls0[ce * 16 + m];
        float ev0 = lv0[ce * 48 + m * 3 + 0];
        float ev1 = lv0[ce * 48 + m * 3 + 1];
        float ev2 = lv0[ce * 48 + m * 3 + 2];
        sS[nl * SSD + 2 * m + 0] = (half_t)(fs * es);
        sS[nl * SSD + 2 * m + 1] =
            (half_t)((fv0 * ev0 + fv1 * ev1 + fv2 * ev2) * INV_S3);
        half_t* vp = Vsh + nl * VPH;
        vp[m * 3 + 0] = (half_t)(fs * ev0);
        vp[m * 3 + 1] = (half_t)(fs * ev1);
        vp[m * 3 + 2] = (half_t)(fs * ev2);
        vp[(16 + m) * 3 + 0] = (half_t)(fv0 * es);
        vp[(16 + m) * 3 + 1] = (half_t)(fv1 * es);
        vp[(16 + m) * 3 + 2] = (half_t)(fv2 * es);
        vp[(32 + m) * 3 + 0] = (half_t)((fv1 * ev2 - fv2 * ev1) * INV_S2);
        vp[(32 + m) * 3 + 1] = (half_t)((fv2 * ev0 - fv0 * ev2) * INV_S2);
        vp[(32 + m) * 3 + 2] = (half_t)((fv0 * ev1 - fv1 * ev0) * INV_S2);
    }

    float lB[40];
    const half_t* gl0 = g_lat0 + (size_t)g * 4096;
#pragma unroll
    for (int h = 0; h < 8; ++h) {
        f32x4 v = ntl_f4(gl0 + ((2 * h + q) * 32 + nl) * 8);
        lB[h * 4 + 0] = v[0]; lB[h * 4 + 1] = v[1];
        lB[h * 4 + 2] = v[2]; lB[h * 4 + 3] = v[3];
    }
    __syncthreads();

#pragma unroll
    for (int j2 = 0; j2 < 4; ++j2) {
        lB[32 + j2] = ld_pk2(sS + nl * SSD + 8 * q + 2 * j2);
        lB[36 + j2] = ld_pk2(sS + nl * SSD + 16 + 8 * q + 2 * j2);
    }

    float hB[32];
#pragma unroll
    for (int c = 0; c < 4; ++c) {  // gw1 (direct; hides stage-0 latency)
        f32x16 d = colstage<20>(b_gw1, lB, c, nl, q);
        silu16(d);
        d2b(d, lane, q, &hB[8 * c], &hB[8 * c + 4]);
    }

    {
        f32x4* wb = &Wbuf[0][0];
#pragma unroll
        for (int k = 0; k < 4; ++k) wb[k * 128 + tid] = st[k];
    }
    __syncthreads();

    float fsacc[8];
    float fvacc[8][3];
#pragma unroll
    for (int s = 0; s < 8; ++s) {
        fsacc[s] = 0.f;
        fvacc[s][0] = fvacc[s][1] = fvacc[s][2] = 0.f;
    }

    for (int c = 0; c < 40; ++c) {
        const int buf = c & 1;
        if (c + 1 < 40) {
#pragma unroll
            for (int k = 0; k < 4; ++k)
                st[k] = ld_f4(gsrc + (size_t)(c + 1) * 512 + k * 128 + tid);
        }
        f32x16 d;
        {
            WFrag f;
            const half_t* wp = reinterpret_cast<const half_t*>(&Wbuf[buf][0]);
#pragma unroll
            for (int h = 0; h < 8; ++h)
                f.a[h] = *reinterpret_cast<const half8*>(
                    wp + ((q + 2 * h) * 32 + nl) * 8);
            d = mfma8w(f, hB);
        }
        if (c < 16) {
            int pu0 = 2 * c, pu1 = pu0 + 1;
            float S0 = (float)sS[nl * SSD + 2 * (pu0 & 15) + (pu0 >> 4)];
            float S1 = (float)sS[nl * SSD + 2 * (pu1 & 15) + (pu1 >> 4)];
#pragma unroll
            for (int r = 0; r < 16; ++r) {
                int a = r >> 2, bb = r & 3, slot = (a & 1) * 4 + bb;
                fsacc[slot] = fmaf((a < 2) ? S0 : S1, d[r], fsacc[slot]);
            }
        } else {
            int w0i = 2 * c - 32, w1i = w0i + 1;
            const half_t* vp = Vsh + nl * VPH;
            float V00 = (float)vp[w0i * 3], V01 = (float)vp[w0i * 3 + 1], V02 = (float)vp[w0i * 3 + 2];
            float V10 = (float)vp[w1i * 3], V11 = (float)vp[w1i * 3 + 1], V12 = (float)vp[w1i * 3 + 2];
#pragma unroll
            for (int r = 0; r < 16; ++r) {
                int a = r >> 2, bb = r & 3, slot = (a & 1) * 4 + bb;
                float x0 = (a < 2) ? V00 : V10;
                float x1 = (a < 2) ? V01 : V11;
                float x2 = (a < 2) ? V02 : V12;
                fvacc[slot][0] = fmaf(x0, d[r], fvacc[slot][0]);
                fvacc[slot][1] = fmaf(x1, d[r], fvacc[slot][1]);
                fvacc[slot][2] = fmaf(x2, d[r], fvacc[slot][2]);
            }
        }
        __builtin_amdgcn_sched_barrier(0);
        if (c + 1 < 40) {
            f32x4* wb = &Wbuf[buf ^ 1][0];
#pragma unroll
            for (int k = 0; k < 4; ++k) wb[k * 128 + tid] = st[k];
        }
        __syncthreads();
    }

    {
        float* fp = gfs2 + e * 16 + 4 * q;
        f32x4 flo = {fsacc[0] * SC_FS, fsacc[1] * SC_FS,
                     fsacc[2] * SC_FS, fsacc[3] * SC_FS};
        f32x4 fhi = {fsacc[4] * SC_FS, fsacc[5] * SC_FS,
                     fsacc[6] * SC_FS, fsacc[7] * SC_FS};
        st_f4(flo, fp);
        st_f4(fhi, fp + 8);
        float t[24];
#pragma unroll
        for (int s = 0; s < 4; ++s) {
#pragma unroll
            for (int c3 = 0; c3 < 3; ++c3) {
                t[s * 3 + c3] = fvacc[s][c3] * SC_FV;
                t[12 + s * 3 + c3] = fvacc[4 + s][c3] * SC_FV;
            }
        }
        float* vlo = gfv2 + e * 48 + 12 * q;
        float* vhi = gfv2 + e * 48 + 24 + 12 * q;
#pragma unroll
        for (int i = 0; i < 3; ++i) {
            f32x4 a = {t[4 * i + 0], t[4 * i + 1], t[4 * i + 2], t[4 * i + 3]};
            f32x4 b = {t[12 + 4 * i + 0], t[12 + 4 * i + 1],
                       t[12 + 4 * i + 2], t[12 + 4 * i + 3]};
            st_f4(a, vlo + 4 * i);
            st_f4(b, vhi + 4 * i);
        }
    }
}

// =====================================================================
// K5: layer1 v2 — 2 waves/block (groups 2b,2b+1) share a double-buffered
// LDS weight stage streaming flw1→flw2→gw1→gw2[16..39] with bridging.
// chunk global idx i lives in Wbuf[i&1].
// =====================================================================
__global__ __launch_bounds__(128, 2) void k_layer1(
    const int* __restrict__ g_eidx, const float* __restrict__ gfs2,
    const float* __restrict__ gfv2, const float* __restrict__ ls1,
    const float* __restrict__ lv1,
    const half_t* __restrict__ b_flw1, const half_t* __restrict__ b_flw2,
    const half_t* __restrict__ b_gw1, const half_t* __restrict__ b_gw2,
    const half_t* __restrict__ g_lat1, float* __restrict__ g_out, int E) {
    __shared__ half_t sS2[2][32 * SSD];
    __shared__ half_t Vsh2[2][32 * VPH];
    __shared__ f32x4 Wbuf[2][640];  // 2 x 10KB (KB=20 chunk max)
    const int tid = threadIdx.x;
    const int lane = tid & 63, nl = lane & 31, q = lane >> 5;
    const int wid = tid >> 6;
    const int g = blockIdx.x * 2 + wid;
    const int e = g * 32 + nl;
    int ce = g_eidx[e];
    half_t* sS = sS2[wid];
    half_t* Vsh = Vsh2[wid];

    const f32x4* wf1 = reinterpret_cast<const f32x4*>(b_flw1);  // 4 x 640
    const f32x4* wf2 = reinterpret_cast<const f32x4*>(b_flw2);  // 1 x 512
    const f32x4* wg1 = reinterpret_cast<const f32x4*>(b_gw1);   // 4 x 640
    const f32x4* wg2 = reinterpret_cast<const f32x4*>(b_gw2);   // mtile m at m*512

    f32x4 st[5];
    ld5(wf1, st, tid);  // chunk idx 0

    // per-wave gather (own group): sS + Vsh
#pragma unroll
    for (int mm = 0; mm < 8; ++mm) {
        int m = q * 8 + mm;
        float fs = ntl_f(gfs2 + e * 16 + m);
        float fv0 = ntl_f(gfv2 + e * 48 + m * 3 + 0);
        float fv1 = ntl_f(gfv2 + e * 48 + m * 3 + 1);
        float fv2 = ntl_f(gfv2 + e * 48 + m * 3 + 2);
        float es = ls1[ce * 16 + m];
        float ev0 = lv1[ce * 48 + m * 3 + 0];
        float ev1 = lv1[ce * 48 + m * 3 + 1];
        float ev2 = lv1[ce * 48 + m * 3 + 2];
        sS[nl * SSD + 2 * m + 0] = (half_t)(fs * es);
        sS[nl * SSD + 2 * m + 1] =
            (half_t)((fv0 * ev0 + fv1 * ev1 + fv2 * ev2) * INV_S3);
        half_t* vp = Vsh + nl * VPH;
        vp[m * 3 + 0] = (half_t)(fs * ev0);
        vp[m * 3 + 1] = (half_t)(fs * ev1);
        vp[m * 3 + 2] = (half_t)(fs * ev2);
        vp[(16 + m) * 3 + 0] = (half_t)(fv0 * es);
        vp[(16 + m) * 3 + 1] = (half_t)(fv1 * es);
        vp[(16 + m) * 3 + 2] = (half_t)(fv2 * es);
        vp[(32 + m) * 3 + 0] = (half_t)((fv1 * ev2 - fv2 * ev1) * INV_S2);
        vp[(32 + m) * 3 + 1] = (half_t)((fv2 * ev0 - fv0 * ev2) * INV_S2);
        vp[(32 + m) * 3 + 2] = (half_t)((fv0 * ev1 - fv1 * ev0) * INV_S2);
    }

    float lB[40];
    const half_t* gl1 = g_lat1 + (size_t)g * 4096;
#pragma unroll
    for (int h = 0; h < 8; ++h) {
        f32x4 v = ntl_f4(gl1 + ((2 * h + q) * 32 + nl) * 8);
        lB[h * 4 + 0] = v[0]; lB[h * 4 + 1] = v[1];
        lB[h * 4 + 2] = v[2]; lB[h * 4 + 3] = v[3];
    }

    wr5(&Wbuf[0][0], st, tid);
    __syncthreads();  // publishes chunk 0

#pragma unroll
    for (int j2 = 0; j2 < 4; ++j2) {
        lB[32 + j2] = ld_pk2(sS + nl * SSD + 8 * q + 2 * j2);
        lB[36 + j2] = ld_pk2(sS + nl * SSD + 16 + 8 * q + 2 * j2);
    }

    float hB[32];
    // stage A: flw1 (KB=20), chunks idx 0..3
#pragma unroll
    for (int c = 0; c < 4; ++c) {
        if (c < 3) ld5(wf1 + (size_t)(c + 1) * 640, st, tid);
        else       ld4(wf2, st, tid);  // bridge -> flw2 (idx 4)
        f32x16 d = colstage_lds<20>(
            reinterpret_cast<const half_t*>(&Wbuf[c & 1][0]), lB, nl, q);
        silu16(d);
        d2b(d, lane, q, &hB[8 * c], &hB[8 * c + 4]);
        __builtin_amdgcn_sched_barrier(0);
        if (c < 3) wr5(&Wbuf[(c + 1) & 1][0], st, tid);
        else       wr4(&Wbuf[(c + 1) & 1][0], st, tid);
        __syncthreads();
    }
    // stage B: flw2 (idx 4, parity 0) -> fw
    float fw[8];
    {
        ld5(wg1, st, tid);  // bridge -> gw1 chunk 0 (idx 5)
        f32x16 d = colstage_lds<16>(
            reinterpret_cast<const half_t*>(&Wbuf[0][0]), hB, nl, q);
#pragma unroll
        for (int r = 0; r < 8; ++r) fw[r] = d[r];
        __builtin_amdgcn_sched_barrier(0);
        wr5(&Wbuf[1][0], st, tid);
        __syncthreads();
    }
    // stage C: gw1 (KB=20), chunks idx 5..8 (parity (5+c)&1 == (c+1)&1)
#pragma unroll
    for (int c = 0; c < 4; ++c) {
        if (c < 3) ld5(wg1 + (size_t)(c + 1) * 640, st, tid);
        else       ld4(wg2 + (size_t)16 * 512, st, tid);  // bridge -> gw2 m16 (idx 9)
        f32x16 d = colstage_lds<20>(
            reinterpret_cast<const half_t*>(&Wbuf[(c + 1) & 1][0]), lB, nl, q);
        silu16(d);
        d2b(d, lane, q, &hB[8 * c], &hB[8 * c + 4]);
        __builtin_amdgcn_sched_barrier(0);
        if (c < 3) wr5(&Wbuf[c & 1][0], st, tid);
        else       wr4(&Wbuf[c & 1][0], st, tid);
        __syncthreads();
    }
    // stage D: gw2 fold, mtiles 16..39 (chunk idx 9+j, parity (j+1)&1)
    float fvacc[8][3];
#pragma unroll
    for (int s = 0; s < 8; ++s) fvacc[s][0] = fvacc[s][1] = fvacc[s][2] = 0.f;
    for (int j = 0; j < 24; ++j) {
        const int pb = (j + 1) & 1;
        if (j < 23) {
#pragma unroll
            for (int k = 0; k < 4; ++k)
                st[k] = ld_f4(wg2 + (size_t)(17 + j) * 512 + k * 128 + tid);
        }
        f32x16 d;
        {
            WFrag f;
            const half_t* wp = reinterpret_cast<const half_t*>(&Wbuf[pb][0]);
#pragma unroll
            for (int h = 0; h < 8; ++h)
                f.a[h] = *reinterpret_cast<const half8*>(
                    wp + ((q + 2 * h) * 32 + nl) * 8);
            d = mfma8w(f, hB);
        }
        {
            int w0i = 2 * j, w1i = 2 * j + 1;
            const half_t* vp = Vsh + nl * VPH;
            float V00 = (float)vp[w0i * 3], V01 = (float)vp[w0i * 3 + 1], V02 = (float)vp[w0i * 3 + 2];
            float V10 = (float)vp[w1i * 3], V11 = (float)vp[w1i * 3 + 1], V12 = (float)vp[w1i * 3 + 2];
#pragma unroll
            for (int r = 0; r < 16; ++r) {
                int a = r >> 2, bb = r & 3, slot = (a & 1) * 4 + bb;
                float x0 = (a < 2) ? V00 : V10;
                float x1 = (a < 2) ? V01 : V11;
                float x2 = (a < 2) ? V02 : V12;
                fvacc[slot][0] = fmaf(x0, d[r], fvacc[slot][0]);
                fvacc[slot][1] = fmaf(x1, d[r], fvacc[slot][1]);
                fvacc[slot][2] = fmaf(x2, d[r], fvacc[slot][2]);
            }
        }
        __builtin_amdgcn_sched_barrier(0);
        if (j < 23) wr4(&Wbuf[pb ^ 1][0], st, tid);
        __syncthreads();
    }
    // epilogue: combine + cross-half reduce + store
    {
        float o0 = 0.f, o1 = 0.f, o2 = 0.f;
#pragma unroll
        for (int s = 0; s < 8; ++s) {
            o0 = fmaf(fw[s], fvacc[s][0], o0);
            o1 = fmaf(fw[s], fvacc[s][1], o1);
            o2 = fmaf(fw[s], fvacc[s][2], o2);
        }
        o0 += __shfl(o0, lane ^ 32, 64);
        o1 += __shfl(o1, lane ^ 32, 64);
        o2 += __shfl(o2, lane ^ 32, 64);
        if (q == 0) {
            g_out[e * 3 + 0] = o0 * SC_OUT;
            g_out[e * 3 + 1] = o1 * SC_OUT;
            g_out[e * 3 + 2] = o2 * SC_OUT;
        }
    }
}

// =====================================================================
extern "C" void kernel_launch(void* const* d_in, const int* in_sizes, int n_in,
                              void* d_out, int out_size, void* d_ws, size_t ws_size,
                              hipStream_t stream) {
    const float* g_ea = (const float*)d_in[0];
    const float* g_na = (const float*)d_in[1];
    const float* g_emb = (const float*)d_in[2];
    const float* g_eu = (const float*)d_in[3];
    const int* g_eidx = (const int*)d_in[4];
    const float* w2b1 = (const float*)d_in[5];
    const float* w2b2 = (const float*)d_in[6];
    const float* lat1w1 = (const float*)d_in[7];
    const float* lat1w2 = (const float*)d_in[8];
    const float* e0w1 = (const float*)d_in[9];
    const float* e0w2 = (const float*)d_in[10];
    const float* e1w1 = (const float*)d_in[11];
    const float* e1w2 = (const float*)d_in[12];
    const float* l2w0w1 = (const float*)d_in[13];
    const float* l2w0w2 = (const float*)d_in[14];
    const float* l2w1w1 = (const float*)d_in[15];
    const float* l2w1w2 = (const float*)d_in[16];
    const float* envws = (const float*)d_in[17];
    const float* envwv = (const float*)d_in[18];
    const float* flw1 = (const float*)d_in[19];
    const float* flw2 = (const float*)d_in[20];
    float* out = (float*)d_out;

    const int E = in_sizes[3];       // 120000
    const int Nn = in_sizes[1] / 4;  // 5000
    const int nblk = E / 32;         // 3750
    const int nblk2 = nblk / 2;      // 1875

    float* p = (float*)d_ws;
    float* gfs = p;  p += (size_t)E * 16;
    float* gfv = p;  p += (size_t)E * 48;
    float* gfs2 = p; p += (size_t)E * 16;
    float* gfv2 = p; p += (size_t)E * 48;
    float* raw0 = p; p += (size_t)Nn * 64;
    float* raw1 = p; p += (size_t)Nn * 64;
    float* ls0 = p;  p += (size_t)Nn * 16;
    float* lv0 = p;  p += (size_t)Nn * 48;
    float* ls1 = p;  p += (size_t)Nn * 16;
    float* lv1 = p;  p += (size_t)Nn * 48;
    half_t* hp = (half_t*)p;
    half_t* lat0h = hp; hp += (size_t)nblk * 4096;
    half_t* lat1h = hp; hp += (size_t)nblk * 4096;

    const int KN[14][2] = {{16, 128}, {128, 128}, {128, 128}, {128, 64},
                           {160, 128}, {128, 128}, {128, 128}, {128, 32},
                           {160, 128}, {128, 1280}, {160, 128}, {128, 1280},
                           {160, 128}, {128, 16}};
    const float* srcs[14] = {w2b1, w2b2, e0w1, e0w2, lat1w1, lat1w2, e1w1, e1w2,
                             l2w0w1, l2w0w2, l2w1w1, l2w1w2, flw1, flw2};
    PackArgs pa;
    half_t* bptr[14];
    for (int i = 0; i < 14; ++i) {
        int K = KN[i][0], N = KN[i][1];
        int Npad = (N + 31) & ~31;
        bptr[i] = hp;
        hp += (size_t)K * Npad;
        pa.src[i] = srcs[i];
        pa.dst[i] = bptr[i];
        pa.K[i] = K;
        pa.N[i] = N;
    }

    k_pack<<<dim3(80, 14), 256, 0, stream>>>(pa);

    const int nzero = Nn * 128;  // raw0 + raw1 contiguous
    k_zero<<<(nzero + 255) / 256, 256, 0, stream>>>(raw0, nzero);

    const int nb2 = (Nn * 16 + 255) / 256;

    k_edge_front<<<nblk2, 128, 0, stream>>>(g_ea, g_na, g_emb, g_eu, g_eidx,
                                            bptr[0], bptr[1], bptr[2], bptr[3],
                                            lat0h, gfs, gfv, raw0, E);
    k_node_lin<<<nb2, 256, 0, stream>>>(raw0, envws, envwv, ls0, lv0, Nn);
    k_fold0<<<nblk2, 128, 0, stream>>>(g_eidx, gfs, gfv, gfs2, gfv2, ls0, lv0,
                                       bptr[8], bptr[9], lat0h, E);
    k_lat0<<<nblk2, 128, 0, stream>>>(g_ea, g_eu, g_eidx, gfs, gfv, ls0, lv0,
                                      bptr[4], bptr[5], bptr[6], bptr[7],
                                      lat0h, lat1h, raw1, E);
    k_node_lin<<<nb2, 256, 0, stream>>>(raw1, envws + 256, envwv + 256, ls1, lv1, Nn);
    k_layer1<<<nblk2, 128, 0, stream>>>(g_eidx, gfs2, gfv2, ls1, lv1,
                                        bptr[12], bptr[13], bptr[10], bptr[11],
                                        lat1h, out, E);
}

// Round 11
// 436.397 us; speedup vs baseline: 1.9852x; 1.9638x over previous
//
#include <hip/hip_runtime.h>

typedef _Float16 half_t;
typedef _Float16 half8 __attribute__((ext_vector_type(8)));
typedef _Float16 half2_t __attribute__((ext_vector_type(2)));
typedef float f32x16 __attribute__((ext_vector_type(16)));
typedef float f32x4 __attribute__((ext_vector_type(4)));

#define DEVINL __device__ __forceinline__

// ---------- constants ----------
#define INV_S3 0.57735026918962576f   // 1/sqrt(3)
#define INV_S2 0.70710678118654752f   // 1/sqrt(2)
#define C_OLD  0.89442719099991588f   // 1/sqrt(1.25)
#define A_COLD 0.44721359549995794f   // 0.5/sqrt(1.25)
#define SC_ENV 0.05590169943749474f   // (1/sqrt(20)) * (1/4)
#define SC_FS  0.17677669529663688f   // 1/sqrt(32)
#define SC_FV  0.14433756729740643f   // 1/sqrt(48)
#define SC_OUT 0.03608439182435161f   // (1/4)/sqrt(48)
#define SSD 34                         // sS stride (halfs)
#define VPH 146                        // V stride (halfs)

DEVINL float silu_f(float x) { return x / (1.f + __expf(-x)); }

DEVINL float poly_cut(float u) {
    float u2 = u * u, u4 = u2 * u2, u6 = u4 * u2;
    float f = 1.f - 28.f * u6 + 48.f * u6 * u - 21.f * u6 * u2;
    return (u < 1.f) ? f : 0.f;
}

DEVINL float pkh(float a, float b) {
    half2_t h; h[0] = (half_t)a; h[1] = (half_t)b;
    return __builtin_bit_cast(float, h);
}
DEVINL float2 uph(float p) {
    half2_t h = __builtin_bit_cast(half2_t, p);
    return make_float2((float)h[0], (float)h[1]);
}
DEVINL half8 mk8(const float* w) {
    f32x4 v = {w[0], w[1], w[2], w[3]};
    return __builtin_bit_cast(half8, v);
}
DEVINL float ld_pk2(const half_t* p) {
    half2_t h; h[0] = p[0]; h[1] = p[1];
    return __builtin_bit_cast(float, h);
}
DEVINL float ntl_f(const float* p) { return __builtin_nontemporal_load(p); }
DEVINL f32x4 ntl_f4(const void* p) {
    return __builtin_nontemporal_load((const f32x4*)p);
}
DEVINL f32x4 ld_f4(const void* p) { return *reinterpret_cast<const f32x4*>(p); }
DEVINL void st_h8(half8 v, half_t* p) { *reinterpret_cast<half8*>(p) = v; }
DEVINL void st_f4(const f32x4& v, float* p) { *reinterpret_cast<f32x4*>(p) = v; }

// =====================================================================
// Edge-column MFMA stage (global weights).
// =====================================================================
template <int KB>  // K/8
DEVINL f32x16 colstage(const half_t* __restrict__ Wg, const float* B, int mtile,
                       int nl, int q) {
    const half_t* ap = Wg + (((size_t)mtile * KB + q) * 32 + nl) * 8;
    constexpr int H = KB / 2;
    f32x16 acc0;
#pragma unroll
    for (int i = 0; i < 16; ++i) acc0[i] = 0.f;
    if constexpr (H < 2) {
        half8 a = *reinterpret_cast<const half8*>(ap);
        acc0 = __builtin_amdgcn_mfma_f32_32x32x16_f16(a, mk8(B), acc0, 0, 0, 0);
        return acc0;
    } else {
        f32x16 acc1;
#pragma unroll
        for (int i = 0; i < 16; ++i) acc1[i] = 0.f;
#pragma unroll
        for (int h = 0; h + 1 < H; h += 2) {
            half8 a0 = *reinterpret_cast<const half8*>(ap + h * 512);
            half8 a1 = *reinterpret_cast<const half8*>(ap + (h + 1) * 512);
            acc0 = __builtin_amdgcn_mfma_f32_32x32x16_f16(a0, mk8(B + h * 4), acc0, 0, 0, 0);
            acc1 = __builtin_amdgcn_mfma_f32_32x32x16_f16(a1, mk8(B + (h + 1) * 4), acc1, 0, 0, 0);
        }
        if constexpr (H & 1) {
            half8 a = *reinterpret_cast<const half8*>(ap + (H - 1) * 512);
            acc0 = __builtin_amdgcn_mfma_f32_32x32x16_f16(a, mk8(B + (H - 1) * 4), acc0, 0, 0, 0);
        }
        return acc0 + acc1;
    }
}

// LDS variant: chunk holds ONE mtile (mtile=0 layout).
template <int KB>
DEVINL f32x16 colstage_lds(const half_t* W, const float* B, int nl, int q) {
    const half_t* ap = W + (q * 32 + nl) * 8;
    constexpr int H = KB / 2;
    f32x16 acc0, acc1;
#pragma unroll
    for (int i = 0; i < 16; ++i) { acc0[i] = 0.f; acc1[i] = 0.f; }
#pragma unroll
    for (int h = 0; h + 1 < H; h += 2) {
        half8 a0 = *reinterpret_cast<const half8*>(ap + h * 512);
        half8 a1 = *reinterpret_cast<const half8*>(ap + (h + 1) * 512);
        acc0 = __builtin_amdgcn_mfma_f32_32x32x16_f16(a0, mk8(B + h * 4), acc0, 0, 0, 0);
        acc1 = __builtin_amdgcn_mfma_f32_32x32x16_f16(a1, mk8(B + (h + 1) * 4), acc1, 0, 0, 0);
    }
    if constexpr (H & 1) {
        half8 a = *reinterpret_cast<const half8*>(ap + (H - 1) * 512);
        acc0 = __builtin_amdgcn_mfma_f32_32x32x16_f16(a, mk8(B + (H - 1) * 4), acc0, 0, 0, 0);
    }
    return acc0 + acc1;
}

struct WFrag { half8 a[8]; };

DEVINL f32x16 mfma8w(const WFrag& f, const float* B) {
    f32x16 acc0, acc1;
#pragma unroll
    for (int i = 0; i < 16; ++i) { acc0[i] = 0.f; acc1[i] = 0.f; }
#pragma unroll
    for (int h = 0; h < 8; h += 2) {
        acc0 = __builtin_amdgcn_mfma_f32_32x32x16_f16(f.a[h], mk8(B + h * 4), acc0, 0, 0, 0);
        acc1 = __builtin_amdgcn_mfma_f32_32x32x16_f16(f.a[h + 1], mk8(B + (h + 1) * 4), acc1, 0, 0, 0);
    }
    return acc0 + acc1;
}

DEVINL void silu16(f32x16& a) {
#pragma unroll
    for (int i = 0; i < 16; ++i) a[i] = silu_f(a[i]);
}

DEVINL void d2b(const f32x16& d, int lane, int q, float* wA, float* wB) {
    float pk[8];
#pragma unroll
    for (int a2 = 0; a2 < 4; ++a2) {
        pk[a2 * 2 + 0] = pkh(d[4 * a2 + 0], d[4 * a2 + 1]);
        pk[a2 * 2 + 1] = pkh(d[4 * a2 + 2], d[4 * a2 + 3]);
    }
#pragma unroll
    for (int t = 0; t < 2; ++t) {
        float k0 = q ? pk[(2 * t + 1) * 2 + 0] : pk[(2 * t) * 2 + 0];
        float k1 = q ? pk[(2 * t + 1) * 2 + 1] : pk[(2 * t) * 2 + 1];
        float s0 = q ? pk[(2 * t) * 2 + 0] : pk[(2 * t + 1) * 2 + 0];
        float s1 = q ? pk[(2 * t) * 2 + 1] : pk[(2 * t + 1) * 2 + 1];
        float r0 = __shfl(s0, lane ^ 32, 64);
        float r1 = __shfl(s1, lane ^ 32, 64);
        float* w = t ? wB : wA;
        w[0] = q ? r0 : k0;
        w[1] = q ? r1 : k1;
        w[2] = q ? k0 : r0;
        w[3] = q ? k1 : r1;
    }
}

// ---- chunk stage helpers (128 threads cooperatively move one mtile) ----
DEVINL void ld5(const f32x4* src, f32x4* st, int tid) {
#pragma unroll
    for (int k = 0; k < 5; ++k) st[k] = ld_f4(src + k * 128 + tid);
}
DEVINL void ld4(const f32x4* src, f32x4* st, int tid) {
#pragma unroll
    for (int k = 0; k < 4; ++k) st[k] = ld_f4(src + k * 128 + tid);
}
DEVINL void wr5(f32x4* dst, const f32x4* st, int tid) {
#pragma unroll
    for (int k = 0; k < 5; ++k) dst[k * 128 + tid] = st[k];
}
DEVINL void wr4(f32x4* dst, const f32x4* st, int tid) {
#pragma unroll
    for (int k = 0; k < 4; ++k) dst[k * 128 + tid] = st[k];
}

// =====================================================================
__global__ __launch_bounds__(256) void k_zero(float* __restrict__ p, int n) {
    int i = blockIdx.x * 256 + threadIdx.x;
    if (i < n) p[i] = 0.f;
}

// =====================================================================
struct PackArgs {
    const float* src[14];
    half_t* dst[14];
    int K[14];
    int N[14];
};

__global__ __launch_bounds__(256) void k_pack(PackArgs pa) {
    int mi = blockIdx.y;
    int K = pa.K[mi], N = pa.N[mi];
    int Npad = (N + 31) & ~31;
    int KB = K >> 3;
    int cells = KB * Npad;
    int cell = blockIdx.x * 256 + threadIdx.x;
    if (cell >= cells) return;
    int nn = cell & 31, r2 = cell >> 5;
    int kblk = r2 % KB, ntile = r2 / KB;
    int n = ntile * 32 + nn;
    const float* W = pa.src[mi];
    half8 v;
#pragma unroll
    for (int j = 0; j < 8; ++j) {
        int k = kblk * 8 + j;
        v[j] = (half_t)((n < N) ? W[k * N + n] : 0.f);
    }
    *reinterpret_cast<half8*>(pa.dst[mi] + (size_t)cell * 8) = v;
}

// =====================================================================
// Counting sort of edges by center node: hist -> scan -> bucket.
// =====================================================================
__global__ __launch_bounds__(256) void k_hist(const int* __restrict__ eidx,
                                              int* __restrict__ cnt, int E) {
    int e = blockIdx.x * 256 + threadIdx.x;
    if (e < E) atomicAdd(&cnt[eidx[e]], 1);
}

__global__ __launch_bounds__(1024) void k_scan(const int* __restrict__ cnt,
                                               int* __restrict__ start,
                                               int* __restrict__ cursor, int Nn) {
    __shared__ int sh[1024];
    const int t = threadIdx.x;
    const int C = 5;  // 5120 >= Nn
    int base = t * C;
    int local[C];
    int s = 0;
#pragma unroll
    for (int j = 0; j < C; ++j) {
        int idx = base + j;
        int v = (idx < Nn) ? cnt[idx] : 0;
        local[j] = v;
        s += v;
    }
    sh[t] = s;
    __syncthreads();
    for (int off = 1; off < 1024; off <<= 1) {
        int v = (t >= off) ? sh[t - off] : 0;
        __syncthreads();
        sh[t] += v;
        __syncthreads();
    }
    int run = sh[t] - s;  // exclusive prefix
#pragma unroll
    for (int j = 0; j < C; ++j) {
        int idx = base + j;
        if (idx < Nn) {
            start[idx] = run;
            cursor[idx] = run;
            run += local[j];
        }
    }
    if (t == 1023) start[Nn] = sh[1023];
}

__global__ __launch_bounds__(256) void k_bucket(const int* __restrict__ eidx,
                                                int* __restrict__ cursor,
                                                int* __restrict__ eord, int E) {
    int e = blockIdx.x * 256 + threadIdx.x;
    if (e < E) {
        int pos = atomicAdd(&cursor[eidx[e]], 1);
        eord[pos] = e;
    }
}

// =====================================================================
// K1: front. 2 independent waves/block, 32 edges each, no LDS.
// Env contributions -> DENSE contrib[e][64] (no atomics).
// =====================================================================
__global__ __launch_bounds__(128, 4) void k_edge_front(
    const float* __restrict__ g_ea, const float* __restrict__ g_na,
    const float* __restrict__ g_emb, const float* __restrict__ g_eu,
    const int* __restrict__ g_eidx,
    const half_t* __restrict__ b_w2b1, const half_t* __restrict__ b_w2b2,
    const half_t* __restrict__ b_e0w1, const half_t* __restrict__ b_e0w2,
    half_t* __restrict__ g_lat0, float* __restrict__ g_fs, float* __restrict__ g_fv,
    float* __restrict__ contrib, int E) {
    const int lane = threadIdx.x & 63, nl = lane & 31, q = lane >> 5;
    const int g = blockIdx.x * 2 + (threadIdx.x >> 6);
    const int e = g * 32 + nl;
    int ce = g_eidx[e];
    (void)ce;
    float4 ea = *reinterpret_cast<const float4*>(g_ea + e * 4);
    float cut = poly_cut(g_eu[e]);

    float xw[4];
    if (q == 0) {
        int ce0 = g_eidx[e];
        int ne = g_eidx[E + e];
        float4 nc = *reinterpret_cast<const float4*>(g_na + ce0 * 4);
        float4 nn = *reinterpret_cast<const float4*>(g_na + ne * 4);
        xw[0] = pkh(nc.x, nc.y); xw[1] = pkh(nc.z, nc.w);
        xw[2] = pkh(nn.x, nn.y); xw[3] = pkh(nn.z, nn.w);
    } else {
        f32x4 m0 = ntl_f4(g_emb + e * 8);
        f32x4 m1 = ntl_f4(g_emb + e * 8 + 4);
        xw[0] = pkh(m0[0], m0[1]); xw[1] = pkh(m0[2], m0[3]);
        xw[2] = pkh(m1[0], m1[1]); xw[3] = pkh(m1[2], m1[3]);
    }

    float hB[32], lB[32];
#pragma unroll
    for (int c = 0; c < 4; ++c) {  // w2b1: K=16
        f32x16 d = colstage<2>(b_w2b1, xw, c, nl, q);
        silu16(d);
        d2b(d, lane, q, &hB[8 * c], &hB[8 * c + 4]);
    }
    half_t* gl = g_lat0 + (size_t)g * 4096;
#pragma unroll
    for (int c = 0; c < 4; ++c) {  // w2b2 -> lat = cut*D
        f32x16 d = colstage<16>(b_w2b2, hB, c, nl, q);
#pragma unroll
        for (int i = 0; i < 16; ++i) d[i] *= cut;
        d2b(d, lane, q, &lB[8 * c], &lB[8 * c + 4]);
        st_h8(mk8(&lB[8 * c]), gl + ((4 * c + q) * 32 + nl) * 8);
        st_h8(mk8(&lB[8 * c + 4]), gl + ((4 * c + 2 + q) * 32 + nl) * 8);
    }
#pragma unroll
    for (int c = 0; c < 4; ++c) {  // e0w1
        f32x16 d = colstage<16>(b_e0w1, lB, c, nl, q);
        silu16(d);
        d2b(d, lane, q, &hB[8 * c], &hB[8 * c + 4]);
    }
    {  // e0w2 both mtiles interleaved
        f32x16 d0 = colstage<16>(b_e0w2, hB, 0, nl, q);
        f32x16 d1 = colstage<16>(b_e0w2, hB, 1, nl, q);
        float* cp = contrib + (size_t)e * 64;
#pragma unroll
        for (int r = 0; r < 16; ++r) {
            int f = (r & 3) + 8 * (r >> 2) + 4 * q;
            int u = f >> 1;
            float v0 = d0[r], v1 = d1[r];
            if ((f & 1) == 0) {
                g_fs[e * 16 + u] = v0 * ea.x;
                cp[u] = v1 * ea.x;
            } else {
                g_fv[e * 48 + u * 3 + 0] = v0 * ea.y;
                g_fv[e * 48 + u * 3 + 1] = v0 * ea.z;
                g_fv[e * 48 + u * 3 + 2] = v0 * ea.w;
                cp[16 + u * 3 + 0] = v1 * ea.y;
                cp[16 + u * 3 + 1] = v1 * ea.z;
                cp[16 + u * 3 + 2] = v1 * ea.w;
            }
        }
    }
}

// =====================================================================
// K2: per-node env aggregation + linear. 64 threads per node (1 wave
// sub-group); coalesced 256B contrib reads via shfl-broadcast indices.
// =====================================================================
__global__ __launch_bounds__(256) void k_node_agg(
    const int* __restrict__ start, const int* __restrict__ eord,
    const float* __restrict__ contrib, const float* __restrict__ wls,
    const float* __restrict__ wlv, float* __restrict__ ls,
    float* __restrict__ lv, int Nn) {
    __shared__ float rawsh[4][64];
    const int t = threadIdx.x & 63;
    const int sub = threadIdx.x >> 6;
    const int n = blockIdx.x * 4 + sub;
    float acc = 0.f;
    if (n < Nn) {
        int s = start[n], en = start[n + 1];
        for (int base = s; base < en; base += 64) {
            int m = en - base; if (m > 64) m = 64;
            int myord = (base + t < en) ? eord[base + t] : 0;
            for (int i = 0; i < m; ++i) {
                int e2 = __shfl(myord, i, 64);
                acc += contrib[(size_t)e2 * 64 + t];
            }
        }
    }
    rawsh[sub][t] = acc;
    __syncthreads();
    if (n < Nn) {
        const float* raws = rawsh[sub];
        if (t < 16) {
            float as = 0.f;
#pragma unroll
            for (int u = 0; u < 16; ++u) as = fmaf(raws[u], wls[u * 16 + t], as);
            ls[n * 16 + t] = as * SC_ENV;
        } else {
            int idx = t - 16;
            int v = idx / 3, c = idx - 3 * v;
            float a = 0.f;
#pragma unroll
            for (int u = 0; u < 16; ++u)
                a = fmaf(raws[16 + u * 3 + c], wlv[u * 16 + v], a);
            lv[n * 48 + v * 3 + c] = a * SC_ENV;
        }
    }
}

// =====================================================================
// K3: FUSED layer0. blockIdx < nblk2: FOLD role (2 fold waves, shared
// double-buffered LDS weight stage, proven ~96us). blockIdx >= nblk2:
// LAT role (2 lat waves, staged weight stream; env -> dense contrib).
// Shared-memory regions carved from one 39424B block per role.
// =====================================================================
__global__ __launch_bounds__(128, 2) void k_foldlat(
    const float* __restrict__ g_ea, const float* __restrict__ g_eu,
    const int* __restrict__ g_eidx,
    const float* __restrict__ g_fs, const float* __restrict__ g_fv,
    float* __restrict__ gfs2, float* __restrict__ gfv2,
    const float* __restrict__ ls0, const float* __restrict__ lv0,
    const half_t* __restrict__ b_lat1w1, const half_t* __restrict__ b_lat1w2,
    const half_t* __restrict__ b_e1w1, const half_t* __restrict__ b_e1w2,
    const half_t* __restrict__ b_gw1, const half_t* __restrict__ b_gw2,
    const half_t* __restrict__ g_lat0, half_t* __restrict__ g_lat1,
    float* __restrict__ contrib, int nblk2, int E) {
    __shared__ __align__(16) char smem[39424];
    const int tid = threadIdx.x;
    const int lane = tid & 63, nl = lane & 31, q = lane >> 5;
    const int wid = tid >> 6;
    const int bid = blockIdx.x;

    if (bid < nblk2) {
        // ============================ FOLD ============================
        half_t* sS = reinterpret_cast<half_t*>(smem) + wid * (32 * SSD);
        half_t* Vsh = reinterpret_cast<half_t*>(smem + 4352) + wid * (32 * VPH);
        f32x4* Wb0 = reinterpret_cast<f32x4*>(smem + 23040);
        f32x4* Wb1 = Wb0 + 512;
        const int g = bid * 2 + wid;
        const int e = g * 32 + nl;
        int ce = g_eidx[e];

        const f32x4* gsrc = reinterpret_cast<const f32x4*>(b_gw2);
        f32x4 st[4];
#pragma unroll
        for (int k = 0; k < 4; ++k) st[k] = ld_f4(gsrc + k * 128 + tid);

#pragma unroll
        for (int mm = 0; mm < 8; ++mm) {
            int m = q * 8 + mm;
            float fs = ntl_f(g_fs + e * 16 + m);
            float fv0 = ntl_f(g_fv + e * 48 + m * 3 + 0);
            float fv1 = ntl_f(g_fv + e * 48 + m * 3 + 1);
            float fv2 = ntl_f(g_fv + e * 48 + m * 3 + 2);
            float es = ls0[ce * 16 + m];
            float ev0 = lv0[ce * 48 + m * 3 + 0];
            float ev1 = lv0[ce * 48 + m * 3 + 1];
            float ev2 = lv0[ce * 48 + m * 3 + 2];
            sS[nl * SSD + 2 * m + 0] = (half_t)(fs * es);
            sS[nl * SSD + 2 * m + 1] =
                (half_t)((fv0 * ev0 + fv1 * ev1 + fv2 * ev2) * INV_S3);
            half_t* vp = Vsh + nl * VPH;
            vp[m * 3 + 0] = (half_t)(fs * ev0);
            vp[m * 3 + 1] = (half_t)(fs * ev1);
            vp[m * 3 + 2] = (half_t)(fs * ev2);
            vp[(16 + m) * 3 + 0] = (half_t)(fv0 * es);
            vp[(16 + m) * 3 + 1] = (half_t)(fv1 * es);
            vp[(16 + m) * 3 + 2] = (half_t)(fv2 * es);
            vp[(32 + m) * 3 + 0] = (half_t)((fv1 * ev2 - fv2 * ev1) * INV_S2);
            vp[(32 + m) * 3 + 1] = (half_t)((fv2 * ev0 - fv0 * ev2) * INV_S2);
            vp[(32 + m) * 3 + 2] = (half_t)((fv0 * ev1 - fv1 * ev0) * INV_S2);
        }

        float lB[40];
        const half_t* gl0 = g_lat0 + (size_t)g * 4096;
#pragma unroll
        for (int h = 0; h < 8; ++h) {
            f32x4 v = ntl_f4(gl0 + ((2 * h + q) * 32 + nl) * 8);
            lB[h * 4 + 0] = v[0]; lB[h * 4 + 1] = v[1];
            lB[h * 4 + 2] = v[2]; lB[h * 4 + 3] = v[3];
        }
        __syncthreads();

#pragma unroll
        for (int j2 = 0; j2 < 4; ++j2) {
            lB[32 + j2] = ld_pk2(sS + nl * SSD + 8 * q + 2 * j2);
            lB[36 + j2] = ld_pk2(sS + nl * SSD + 16 + 8 * q + 2 * j2);
        }

        float hB[32];
#pragma unroll
        for (int c = 0; c < 4; ++c) {  // gw1 direct (hides stage-0 latency)
            f32x16 d = colstage<20>(b_gw1, lB, c, nl, q);
            silu16(d);
            d2b(d, lane, q, &hB[8 * c], &hB[8 * c + 4]);
        }

#pragma unroll
        for (int k = 0; k < 4; ++k) Wb0[k * 128 + tid] = st[k];
        __syncthreads();

        float fsacc[8];
        float fvacc[8][3];
#pragma unroll
        for (int s = 0; s < 8; ++s) {
            fsacc[s] = 0.f;
            fvacc[s][0] = fvacc[s][1] = fvacc[s][2] = 0.f;
        }

        for (int c = 0; c < 40; ++c) {
            const int buf = c & 1;
            f32x4* cur = buf ? Wb1 : Wb0;
            f32x4* nxt = buf ? Wb0 : Wb1;
            if (c + 1 < 40) {
#pragma unroll
                for (int k = 0; k < 4; ++k)
                    st[k] = ld_f4(gsrc + (size_t)(c + 1) * 512 + k * 128 + tid);
            }
            f32x16 d;
            {
                WFrag f;
                const half_t* wp = reinterpret_cast<const half_t*>(cur);
#pragma unroll
                for (int h = 0; h < 8; ++h)
                    f.a[h] = *reinterpret_cast<const half8*>(
                        wp + ((q + 2 * h) * 32 + nl) * 8);
                d = mfma8w(f, hB);
            }
            if (c < 16) {
                int pu0 = 2 * c, pu1 = pu0 + 1;
                float S0 = (float)sS[nl * SSD + 2 * (pu0 & 15) + (pu0 >> 4)];
                float S1 = (float)sS[nl * SSD + 2 * (pu1 & 15) + (pu1 >> 4)];
#pragma unroll
                for (int r = 0; r < 16; ++r) {
                    int a = r >> 2, bb = r & 3, slot = (a & 1) * 4 + bb;
                    fsacc[slot] = fmaf((a < 2) ? S0 : S1, d[r], fsacc[slot]);
                }
            } else {
                int w0i = 2 * c - 32, w1i = w0i + 1;
                const half_t* vp = Vsh + nl * VPH;
                float V00 = (float)vp[w0i * 3], V01 = (float)vp[w0i * 3 + 1], V02 = (float)vp[w0i * 3 + 2];
                float V10 = (float)vp[w1i * 3], V11 = (float)vp[w1i * 3 + 1], V12 = (float)vp[w1i * 3 + 2];
#pragma unroll
                for (int r = 0; r < 16; ++r) {
                    int a = r >> 2, bb = r & 3, slot = (a & 1) * 4 + bb;
                    float x0 = (a < 2) ? V00 : V10;
                    float x1 = (a < 2) ? V01 : V11;
                    float x2 = (a < 2) ? V02 : V12;
                    fvacc[slot][0] = fmaf(x0, d[r], fvacc[slot][0]);
                    fvacc[slot][1] = fmaf(x1, d[r], fvacc[slot][1]);
                    fvacc[slot][2] = fmaf(x2, d[r], fvacc[slot][2]);
                }
            }
            __builtin_amdgcn_sched_barrier(0);
            if (c + 1 < 40) {
#pragma unroll
                for (int k = 0; k < 4; ++k) nxt[k * 128 + tid] = st[k];
            }
            __syncthreads();
        }

        {
            float* fp = gfs2 + e * 16 + 4 * q;
            f32x4 flo = {fsacc[0] * SC_FS, fsacc[1] * SC_FS,
                         fsacc[2] * SC_FS, fsacc[3] * SC_FS};
            f32x4 fhi = {fsacc[4] * SC_FS, fsacc[5] * SC_FS,
                         fsacc[6] * SC_FS, fsacc[7] * SC_FS};
            st_f4(flo, fp);
            st_f4(fhi, fp + 8);
            float t2[24];
#pragma unroll
            for (int s = 0; s < 4; ++s) {
#pragma unroll
                for (int c3 = 0; c3 < 3; ++c3) {
                    t2[s * 3 + c3] = fvacc[s][c3] * SC_FV;
                    t2[12 + s * 3 + c3] = fvacc[4 + s][c3] * SC_FV;
                }
            }
            float* vlo = gfv2 + e * 48 + 12 * q;
            float* vhi = gfv2 + e * 48 + 24 + 12 * q;
#pragma unroll
            for (int i = 0; i < 3; ++i) {
                f32x4 a = {t2[4 * i + 0], t2[4 * i + 1], t2[4 * i + 2], t2[4 * i + 3]};
                f32x4 b = {t2[12 + 4 * i + 0], t2[12 + 4 * i + 1],
                           t2[12 + 4 * i + 2], t2[12 + 4 * i + 3]};
                st_f4(a, vlo + 4 * i);
                st_f4(b, vhi + 4 * i);
            }
        }
    } else {
        // ============================ LAT =============================
        half_t* sS = reinterpret_cast<half_t*>(smem) + wid * (32 * SSD);
        f32x4* Wb0 = reinterpret_cast<f32x4*>(smem + 4352);
        f32x4* Wb1 = Wb0 + 640;
        const int b = bid - nblk2;
        const int g = b * 2 + wid;
        const int e = g * 32 + nl;
        int ce = g_eidx[e];

        const f32x4* w11 = reinterpret_cast<const f32x4*>(b_lat1w1);  // 4 x 640
        const f32x4* w12 = reinterpret_cast<const f32x4*>(b_lat1w2);  // 4 x 512
        const f32x4* w21 = reinterpret_cast<const f32x4*>(b_e1w1);    // 4 x 512
        const f32x4* w22 = reinterpret_cast<const f32x4*>(b_e1w2);    // 1 x 512

        f32x4 st[5];
        ld5(w11, st, tid);  // chunk 0 in flight

#pragma unroll
        for (int mm = 0; mm < 8; ++mm) {
            int m = q * 8 + mm;
            float fs = ntl_f(g_fs + e * 16 + m);
            float fv0 = ntl_f(g_fv + e * 48 + m * 3 + 0);
            float fv1 = ntl_f(g_fv + e * 48 + m * 3 + 1);
            float fv2 = ntl_f(g_fv + e * 48 + m * 3 + 2);
            float es = ls0[ce * 16 + m];
            float ev0 = lv0[ce * 48 + m * 3 + 0];
            float ev1 = lv0[ce * 48 + m * 3 + 1];
            float ev2 = lv0[ce * 48 + m * 3 + 2];
            sS[nl * SSD + 2 * m + 0] = (half_t)(fs * es);
            sS[nl * SSD + 2 * m + 1] =
                (half_t)((fv0 * ev0 + fv1 * ev1 + fv2 * ev2) * INV_S3);
        }

        float lB[40];
        const half_t* gl0 = g_lat0 + (size_t)g * 4096;
#pragma unroll
        for (int h = 0; h < 8; ++h) {
            f32x4 v = ntl_f4(gl0 + ((2 * h + q) * 32 + nl) * 8);
            lB[h * 4 + 0] = v[0]; lB[h * 4 + 1] = v[1];
            lB[h * 4 + 2] = v[2]; lB[h * 4 + 3] = v[3];
        }
        float4 ea = *reinterpret_cast<const float4*>(g_ea + e * 4);
        float cut = poly_cut(g_eu[e]);

        wr5(Wb0, st, tid);
        __syncthreads();  // publishes chunk 0

#pragma unroll
        for (int j2 = 0; j2 < 4; ++j2) {
            lB[32 + j2] = ld_pk2(sS + nl * SSD + 8 * q + 2 * j2);
            lB[36 + j2] = ld_pk2(sS + nl * SSD + 16 + 8 * q + 2 * j2);
        }

        float hB[32];
        // stage A: lat1w1 (KB=20), chunks idx 0..3
#pragma unroll
        for (int c = 0; c < 4; ++c) {
            if (c < 3) ld5(w11 + (size_t)(c + 1) * 640, st, tid);
            else       ld4(w12, st, tid);  // bridge -> lat1w2 (idx 4)
            f32x16 d = colstage_lds<20>(
                reinterpret_cast<const half_t*>((c & 1) ? Wb1 : Wb0), lB, nl, q);
            silu16(d);
            d2b(d, lane, q, &hB[8 * c], &hB[8 * c + 4]);
            __builtin_amdgcn_sched_barrier(0);
            if (c < 3) wr5(((c + 1) & 1) ? Wb1 : Wb0, st, tid);
            else       wr4(((c + 1) & 1) ? Wb1 : Wb0, st, tid);
            __syncthreads();
        }
        // stage B: lat1w2 (KB=16), chunks idx 4..7 (parity == c&1)
        half_t* gl1 = g_lat1 + (size_t)g * 4096;
        float sc = A_COLD * cut;
#pragma unroll
        for (int c = 0; c < 4; ++c) {
            if (c < 3) ld4(w12 + (size_t)(c + 1) * 512, st, tid);
            else       ld4(w21, st, tid);  // bridge -> e1w1 (idx 8)
            f32x16 d = colstage_lds<16>(
                reinterpret_cast<const half_t*>((c & 1) ? Wb1 : Wb0), hB, nl, q);
#pragma unroll
            for (int i = 0; i < 16; ++i) d[i] *= sc;
            float nw[8];
            d2b(d, lane, q, nw, nw + 4);
#pragma unroll
            for (int p = 0; p < 8; ++p) {
                float2 o = uph(lB[8 * c + p]);
                float2 nn2 = uph(nw[p]);
                lB[8 * c + p] = pkh(C_OLD * o.x + nn2.x, C_OLD * o.y + nn2.y);
            }
            st_h8(mk8(&lB[8 * c]), gl1 + ((4 * c + q) * 32 + nl) * 8);
            st_h8(mk8(&lB[8 * c + 4]), gl1 + ((4 * c + 2 + q) * 32 + nl) * 8);
            __builtin_amdgcn_sched_barrier(0);
            wr4(((c + 1) & 1) ? Wb1 : Wb0, st, tid);
            __syncthreads();
        }
        // stage C: e1w1 (KB=16), chunks idx 8..11 (parity == c&1)
#pragma unroll
        for (int c = 0; c < 4; ++c) {
            if (c == 3) ld4(w22, st, tid);  // bridge -> e1w2 (idx 12)
            f32x16 d = colstage_lds<16>(
                reinterpret_cast<const half_t*>((c & 1) ? Wb1 : Wb0), lB, nl, q);
            silu16(d);
            d2b(d, lane, q, &hB[8 * c], &hB[8 * c + 4]);
            if (c < 3) ld4(w21 + (size_t)(c + 1) * 512, st, tid);
            __builtin_amdgcn_sched_barrier(0);
            wr4(((c + 1) & 1) ? Wb1 : Wb0, st, tid);
            __syncthreads();
        }
        // stage D: e1w2 (idx 12, parity 0) -> dense contrib (no atomics)
        {
            f32x16 d = colstage_lds<16>(
                reinterpret_cast<const half_t*>(Wb0), hB, nl, q);
            float* cp = contrib + (size_t)e * 64;
#pragma unroll
            for (int r = 0; r < 16; ++r) {
                int f = (r & 3) + 8 * (r >> 2) + 4 * q;
                int u = f >> 1;
                float val = d[r];
                if ((f & 1) == 0) {
                    cp[u] = val * ea.x;
                } else {
                    cp[16 + u * 3 + 0] = val * ea.y;
                    cp[16 + u * 3 + 1] = val * ea.z;
                    cp[16 + u * 3 + 2] = val * ea.w;
                }
            }
        }
    }
}

// =====================================================================
// K5: layer1 v2 — staged weight stream (unchanged from round 10).
// =====================================================================
__global__ __launch_bounds__(128, 2) void k_layer1(
    const int* __restrict__ g_eidx, const float* __restrict__ gfs2,
    const float* __restrict__ gfv2, const float* __restrict__ ls1,
    const float* __restrict__ lv1,
    const half_t* __restrict__ b_flw1, const half_t* __restrict__ b_flw2,
    const half_t* __restrict__ b_gw1, const half_t* __restrict__ b_gw2,
    const half_t* __restrict__ g_lat1, float* __restrict__ g_out, int E) {
    __shared__ half_t sS2[2][32 * SSD];
    __shared__ half_t Vsh2[2][32 * VPH];
    __shared__ f32x4 Wbuf[2][640];
    const int tid = threadIdx.x;
    const int lane = tid & 63, nl = lane & 31, q = lane >> 5;
    const int wid = tid >> 6;
    const int g = blockIdx.x * 2 + wid;
    const int e = g * 32 + nl;
    int ce = g_eidx[e];
    half_t* sS = sS2[wid];
    half_t* Vsh = Vsh2[wid];

    const f32x4* wf1 = reinterpret_cast<const f32x4*>(b_flw1);
    const f32x4* wf2 = reinterpret_cast<const f32x4*>(b_flw2);
    const f32x4* wg1 = reinterpret_cast<const f32x4*>(b_gw1);
    const f32x4* wg2 = reinterpret_cast<const f32x4*>(b_gw2);

    f32x4 st[5];
    ld5(wf1, st, tid);

#pragma unroll
    for (int mm = 0; mm < 8; ++mm) {
        int m = q * 8 + mm;
        float fs = ntl_f(gfs2 + e * 16 + m);
        float fv0 = ntl_f(gfv2 + e * 48 + m * 3 + 0);
        float fv1 = ntl_f(gfv2 + e * 48 + m * 3 + 1);
        float fv2 = ntl_f(gfv2 + e * 48 + m * 3 + 2);
        float es = ls1[ce * 16 + m];
        float ev0 = lv1[ce * 48 + m * 3 + 0];
        float ev1 = lv1[ce * 48 + m * 3 + 1];
        float ev2 = lv1[ce * 48 + m * 3 + 2];
        sS[nl * SSD + 2 * m + 0] = (half_t)(fs * es);
        sS[nl * SSD + 2 * m + 1] =
            (half_t)((fv0 * ev0 + fv1 * ev1 + fv2 * ev2) * INV_S3);
        half_t* vp = Vsh + nl * VPH;
        vp[m * 3 + 0] = (half_t)(fs * ev0);
        vp[m * 3 + 1] = (half_t)(fs * ev1);
        vp[m * 3 + 2] = (half_t)(fs * ev2);
        vp[(16 + m) * 3 + 0] = (half_t)(fv0 * es);
        vp[(16 + m) * 3 + 1] = (half_t)(fv1 * es);
        vp[(16 + m) * 3 + 2] = (half_t)(fv2 * es);
        vp[(32 + m) * 3 + 0] = (half_t)((fv1 * ev2 - fv2 * ev1) * INV_S2);
        vp[(32 + m) * 3 + 1] = (half_t)((fv2 * ev0 - fv0 * ev2) * INV_S2);
        vp[(32 + m) * 3 + 2] = (half_t)((fv0 * ev1 - fv1 * ev0) * INV_S2);
    }

    float lB[40];
    const half_t* gl1 = g_lat1 + (size_t)g * 4096;
#pragma unroll
    for (int h = 0; h < 8; ++h) {
        f32x4 v = ntl_f4(gl1 + ((2 * h + q) * 32 + nl) * 8);
        lB[h * 4 + 0] = v[0]; lB[h * 4 + 1] = v[1];
        lB[h * 4 + 2] = v[2]; lB[h * 4 + 3] = v[3];
    }

    wr5(&Wbuf[0][0], st, tid);
    __syncthreads();

#pragma unroll
    for (int j2 = 0; j2 < 4; ++j2) {
        lB[32 + j2] = ld_pk2(sS + nl * SSD + 8 * q + 2 * j2);
        lB[36 + j2] = ld_pk2(sS + nl * SSD + 16 + 8 * q + 2 * j2);
    }

    float hB[32];
#pragma unroll
    for (int c = 0; c < 4; ++c) {  // flw1, chunks 0..3
        if (c < 3) ld5(wf1 + (size_t)(c + 1) * 640, st, tid);
        else       ld4(wf2, st, tid);
        f32x16 d = colstage_lds<20>(
            reinterpret_cast<const half_t*>(&Wbuf[c & 1][0]), lB, nl, q);
        silu16(d);
        d2b(d, lane, q, &hB[8 * c], &hB[8 * c + 4]);
        __builtin_amdgcn_sched_barrier(0);
        if (c < 3) wr5(&Wbuf[(c + 1) & 1][0], st, tid);
        else       wr4(&Wbuf[(c + 1) & 1][0], st, tid);
        __syncthreads();
    }
    float fw[8];
    {  // flw2 (idx 4, parity 0)
        ld5(wg1, st, tid);
        f32x16 d = colstage_lds<16>(
            reinterpret_cast<const half_t*>(&Wbuf[0][0]), hB, nl, q);
#pragma unroll
        for (int r = 0; r < 8; ++r) fw[r] = d[r];
        __builtin_amdgcn_sched_barrier(0);
        wr5(&Wbuf[1][0], st, tid);
        __syncthreads();
    }
#pragma unroll
    for (int c = 0; c < 4; ++c) {  // gw1, chunks idx 5..8
        if (c < 3) ld5(wg1 + (size_t)(c + 1) * 640, st, tid);
        else       ld4(wg2 + (size_t)16 * 512, st, tid);
        f32x16 d = colstage_lds<20>(
            reinterpret_cast<const half_t*>(&Wbuf[(c + 1) & 1][0]), lB, nl, q);
        silu16(d);
        d2b(d, lane, q, &hB[8 * c], &hB[8 * c + 4]);
        __builtin_amdgcn_sched_barrier(0);
        if (c < 3) wr5(&Wbuf[c & 1][0], st, tid);
        else       wr4(&Wbuf[c & 1][0], st, tid);
        __syncthreads();
    }
    float fvacc[8][3];
#pragma unroll
    for (int s = 0; s < 8; ++s) fvacc[s][0] = fvacc[s][1] = fvacc[s][2] = 0.f;
    for (int j = 0; j < 24; ++j) {  // gw2 fold, mtiles 16..39
        const int pb = (j + 1) & 1;
        if (j < 23) {
#pragma unroll
            for (int k = 0; k < 4; ++k)
                st[k] = ld_f4(wg2 + (size_t)(17 + j) * 512 + k * 128 + tid);
        }
        f32x16 d;
        {
            WFrag f;
            const half_t* wp = reinterpret_cast<const half_t*>(&Wbuf[pb][0]);
#pragma unroll
            for (int h = 0; h < 8; ++h)
                f.a[h] = *reinterpret_cast<const half8*>(
                    wp + ((q + 2 * h) * 32 + nl) * 8);
            d = mfma8w(f, hB);
        }
        {
            int w0i = 2 * j, w1i = 2 * j + 1;
            const half_t* vp = Vsh + nl * VPH;
            float V00 = (float)vp[w0i * 3], V01 = (float)vp[w0i * 3 + 1], V02 = (float)vp[w0i * 3 + 2];
            float V10 = (float)vp[w1i * 3], V11 = (float)vp[w1i * 3 + 1], V12 = (float)vp[w1i * 3 + 2];
#pragma unroll
            for (int r = 0; r < 16; ++r) {
                int a = r >> 2, bb = r & 3, slot = (a & 1) * 4 + bb;
                float x0 = (a < 2) ? V00 : V10;
                float x1 = (a < 2) ? V01 : V11;
                float x2 = (a < 2) ? V02 : V12;
                fvacc[slot][0] = fmaf(x0, d[r], fvacc[slot][0]);
                fvacc[slot][1] = fmaf(x1, d[r], fvacc[slot][1]);
                fvacc[slot][2] = fmaf(x2, d[r], fvacc[slot][2]);
            }
        }
        __builtin_amdgcn_sched_barrier(0);
        if (j < 23) wr4(&Wbuf[pb ^ 1][0], st, tid);
        __syncthreads();
    }
    {
        float o0 = 0.f, o1 = 0.f, o2 = 0.f;
#pragma unroll
        for (int s = 0; s < 8; ++s) {
            o0 = fmaf(fw[s], fvacc[s][0], o0);
            o1 = fmaf(fw[s], fvacc[s][1], o1);
            o2 = fmaf(fw[s], fvacc[s][2], o2);
        }
        o0 += __shfl(o0, lane ^ 32, 64);
        o1 += __shfl(o1, lane ^ 32, 64);
        o2 += __shfl(o2, lane ^ 32, 64);
        if (q == 0) {
            g_out[e * 3 + 0] = o0 * SC_OUT;
            g_out[e * 3 + 1] = o1 * SC_OUT;
            g_out[e * 3 + 2] = o2 * SC_OUT;
        }
    }
}

// =====================================================================
extern "C" void kernel_launch(void* const* d_in, const int* in_sizes, int n_in,
                              void* d_out, int out_size, void* d_ws, size_t ws_size,
                              hipStream_t stream) {
    const float* g_ea = (const float*)d_in[0];
    const float* g_na = (const float*)d_in[1];
    const float* g_emb = (const float*)d_in[2];
    const float* g_eu = (const float*)d_in[3];
    const int* g_eidx = (const int*)d_in[4];
    const float* w2b1 = (const float*)d_in[5];
    const float* w2b2 = (const float*)d_in[6];
    const float* lat1w1 = (const float*)d_in[7];
    const float* lat1w2 = (const float*)d_in[8];
    const float* e0w1 = (const float*)d_in[9];
    const float* e0w2 = (const float*)d_in[10];
    const float* e1w1 = (const float*)d_in[11];
    const float* e1w2 = (const float*)d_in[12];
    const float* l2w0w1 = (const float*)d_in[13];
    const float* l2w0w2 = (const float*)d_in[14];
    const float* l2w1w1 = (const float*)d_in[15];
    const float* l2w1w2 = (const float*)d_in[16];
    const float* envws = (const float*)d_in[17];
    const float* envwv = (const float*)d_in[18];
    const float* flw1 = (const float*)d_in[19];
    const float* flw2 = (const float*)d_in[20];
    float* out = (float*)d_out;

    const int E = in_sizes[3];       // 120000
    const int Nn = in_sizes[1] / 4;  // 5000
    const int nblk = E / 32;         // 3750
    const int nblk2 = nblk / 2;      // 1875

    float* p = (float*)d_ws;
    float* gfs = p;  p += (size_t)E * 16;
    float* gfv = p;  p += (size_t)E * 48;
    float* gfs2 = p; p += (size_t)E * 16;
    float* gfv2 = p; p += (size_t)E * 48;
    float* contrib = p; p += (size_t)E * 64;
    float* ls0 = p;  p += (size_t)Nn * 16;
    float* lv0 = p;  p += (size_t)Nn * 48;
    float* ls1 = p;  p += (size_t)Nn * 16;
    float* lv1 = p;  p += (size_t)Nn * 48;
    half_t* hp = (half_t*)p;
    half_t* lat0h = hp; hp += (size_t)nblk * 4096;
    half_t* lat1h = hp; hp += (size_t)nblk * 4096;

    const int KN[14][2] = {{16, 128}, {128, 128}, {128, 128}, {128, 64},
                           {160, 128}, {128, 128}, {128, 128}, {128, 32},
                           {160, 128}, {128, 1280}, {160, 128}, {128, 1280},
                           {160, 128}, {128, 16}};
    const float* srcs[14] = {w2b1, w2b2, e0w1, e0w2, lat1w1, lat1w2, e1w1, e1w2,
                             l2w0w1, l2w0w2, l2w1w1, l2w1w2, flw1, flw2};
    PackArgs pa;
    half_t* bptr[14];
    for (int i = 0; i < 14; ++i) {
        int K = KN[i][0], N = KN[i][1];
        int Npad = (N + 31) & ~31;
        bptr[i] = hp;
        hp += (size_t)K * Npad;
        pa.src[i] = srcs[i];
        pa.dst[i] = bptr[i];
        pa.K[i] = K;
        pa.N[i] = N;
    }
    // int workspace (sorting), after weight packs
    int* ip = (int*)hp;
    int* cnt = ip;    ip += Nn;
    int* cursor = ip; ip += Nn;
    int* startp = ip; ip += Nn + 1;
    int* eord = ip;   ip += E;

    k_pack<<<dim3(80, 14), 256, 0, stream>>>(pa);
    k_zero<<<(Nn + 255) / 256, 256, 0, stream>>>((float*)cnt, Nn);
    k_hist<<<(E + 255) / 256, 256, 0, stream>>>(g_eidx, cnt, E);
    k_scan<<<1, 1024, 0, stream>>>(cnt, startp, cursor, Nn);
    k_bucket<<<(E + 255) / 256, 256, 0, stream>>>(g_eidx, cursor, eord, E);

    k_edge_front<<<nblk2, 128, 0, stream>>>(g_ea, g_na, g_emb, g_eu, g_eidx,
                                            bptr[0], bptr[1], bptr[2], bptr[3],
                                            lat0h, gfs, gfv, contrib, E);
    const int nagg = (Nn + 3) / 4;
    k_node_agg<<<nagg, 256, 0, stream>>>(startp, eord, contrib, envws, envwv,
                                         ls0, lv0, Nn);
    k_foldlat<<<nblk, 128, 0, stream>>>(g_ea, g_eu, g_eidx, gfs, gfv, gfs2, gfv2,
                                        ls0, lv0, bptr[4], bptr[5], bptr[6],
                                        bptr[7], bptr[8], bptr[9], lat0h, lat1h,
                                        contrib, nblk2, E);
    k_node_agg<<<nagg, 256, 0, stream>>>(startp, eord, contrib, envws + 256,
                                         envwv + 256, ls1, lv1, Nn);
    k_layer1<<<nblk2, 128, 0, stream>>>(g_eidx, gfs2, gfv2, ls1, lv1,
                                        bptr[12], bptr[13], bptr[10], bptr[11],
                                        lat1h, out, E);
}

// Round 12
// 429.869 us; speedup vs baseline: 2.0154x; 1.0152x over previous
//
#include <hip/hip_runtime.h>

typedef _Float16 half_t;
typedef _Float16 half8 __attribute__((ext_vector_type(8)));
typedef _Float16 half2_t __attribute__((ext_vector_type(2)));
typedef float f32x16 __attribute__((ext_vector_type(16)));
typedef float f32x4 __attribute__((ext_vector_type(4)));

#define DEVINL __device__ __forceinline__

// ---------- constants ----------
#define INV_S3 0.57735026918962576f   // 1/sqrt(3)
#define INV_S2 0.70710678118654752f   // 1/sqrt(2)
#define C_OLD  0.89442719099991588f   // 1/sqrt(1.25)
#define A_COLD 0.44721359549995794f   // 0.5/sqrt(1.25)
#define SC_ENV 0.05590169943749474f   // (1/sqrt(20)) * (1/4)
#define SC_FS  0.17677669529663688f   // 1/sqrt(32)
#define SC_FV  0.14433756729740643f   // 1/sqrt(48)
#define SC_OUT 0.03608439182435161f   // (1/4)/sqrt(48)
#define SSD 34                         // sS stride (halfs)
#define VPH 146                        // V stride (halfs)

DEVINL float silu_f(float x) { return x / (1.f + __expf(-x)); }

DEVINL float poly_cut(float u) {
    float u2 = u * u, u4 = u2 * u2, u6 = u4 * u2;
    float f = 1.f - 28.f * u6 + 48.f * u6 * u - 21.f * u6 * u2;
    return (u < 1.f) ? f : 0.f;
}

DEVINL float pkh(float a, float b) {
    half2_t h; h[0] = (half_t)a; h[1] = (half_t)b;
    return __builtin_bit_cast(float, h);
}
DEVINL float2 uph(float p) {
    half2_t h = __builtin_bit_cast(half2_t, p);
    return make_float2((float)h[0], (float)h[1]);
}
DEVINL half8 mk8(const float* w) {
    f32x4 v = {w[0], w[1], w[2], w[3]};
    return __builtin_bit_cast(half8, v);
}
DEVINL float ld_pk2(const half_t* p) {
    half2_t h; h[0] = p[0]; h[1] = p[1];
    return __builtin_bit_cast(float, h);
}
DEVINL float ntl_f(const float* p) { return __builtin_nontemporal_load(p); }
DEVINL f32x4 ntl_f4(const void* p) {
    return __builtin_nontemporal_load((const f32x4*)p);
}
DEVINL f32x4 ld_f4(const void* p) { return *reinterpret_cast<const f32x4*>(p); }
DEVINL void st_h8(half8 v, half_t* p) { *reinterpret_cast<half8*>(p) = v; }
DEVINL void st_f4(const f32x4& v, float* p) { *reinterpret_cast<f32x4*>(p) = v; }

// =====================================================================
// Edge-column MFMA stage (global weights).
// =====================================================================
template <int KB>  // K/8
DEVINL f32x16 colstage(const half_t* __restrict__ Wg, const float* B, int mtile,
                       int nl, int q) {
    const half_t* ap = Wg + (((size_t)mtile * KB + q) * 32 + nl) * 8;
    constexpr int H = KB / 2;
    f32x16 acc0;
#pragma unroll
    for (int i = 0; i < 16; ++i) acc0[i] = 0.f;
    if constexpr (H < 2) {
        half8 a = *reinterpret_cast<const half8*>(ap);
        acc0 = __builtin_amdgcn_mfma_f32_32x32x16_f16(a, mk8(B), acc0, 0, 0, 0);
        return acc0;
    } else {
        f32x16 acc1;
#pragma unroll
        for (int i = 0; i < 16; ++i) acc1[i] = 0.f;
#pragma unroll
        for (int h = 0; h + 1 < H; h += 2) {
            half8 a0 = *reinterpret_cast<const half8*>(ap + h * 512);
            half8 a1 = *reinterpret_cast<const half8*>(ap + (h + 1) * 512);
            acc0 = __builtin_amdgcn_mfma_f32_32x32x16_f16(a0, mk8(B + h * 4), acc0, 0, 0, 0);
            acc1 = __builtin_amdgcn_mfma_f32_32x32x16_f16(a1, mk8(B + (h + 1) * 4), acc1, 0, 0, 0);
        }
        if constexpr (H & 1) {
            half8 a = *reinterpret_cast<const half8*>(ap + (H - 1) * 512);
            acc0 = __builtin_amdgcn_mfma_f32_32x32x16_f16(a, mk8(B + (H - 1) * 4), acc0, 0, 0, 0);
        }
        return acc0 + acc1;
    }
}

// LDS variant: chunk holds ONE mtile (mtile=0 layout).
template <int KB>
DEVINL f32x16 colstage_lds(const half_t* W, const float* B, int nl, int q) {
    const half_t* ap = W + (q * 32 + nl) * 8;
    constexpr int H = KB / 2;
    f32x16 acc0, acc1;
#pragma unroll
    for (int i = 0; i < 16; ++i) { acc0[i] = 0.f; acc1[i] = 0.f; }
#pragma unroll
    for (int h = 0; h + 1 < H; h += 2) {
        half8 a0 = *reinterpret_cast<const half8*>(ap + h * 512);
        half8 a1 = *reinterpret_cast<const half8*>(ap + (h + 1) * 512);
        acc0 = __builtin_amdgcn_mfma_f32_32x32x16_f16(a0, mk8(B + h * 4), acc0, 0, 0, 0);
        acc1 = __builtin_amdgcn_mfma_f32_32x32x16_f16(a1, mk8(B + (h + 1) * 4), acc1, 0, 0, 0);
    }
    if constexpr (H & 1) {
        half8 a = *reinterpret_cast<const half8*>(ap + (H - 1) * 512);
        acc0 = __builtin_amdgcn_mfma_f32_32x32x16_f16(a, mk8(B + (H - 1) * 4), acc0, 0, 0, 0);
    }
    return acc0 + acc1;
}

struct WFrag { half8 a[8]; };

DEVINL f32x16 mfma8w(const WFrag& f, const float* B) {
    f32x16 acc0, acc1;
#pragma unroll
    for (int i = 0; i < 16; ++i) { acc0[i] = 0.f; acc1[i] = 0.f; }
#pragma unroll
    for (int h = 0; h < 8; h += 2) {
        acc0 = __builtin_amdgcn_mfma_f32_32x32x16_f16(f.a[h], mk8(B + h * 4), acc0, 0, 0, 0);
        acc1 = __builtin_amdgcn_mfma_f32_32x32x16_f16(f.a[h + 1], mk8(B + (h + 1) * 4), acc1, 0, 0, 0);
    }
    return acc0 + acc1;
}

DEVINL void silu16(f32x16& a) {
#pragma unroll
    for (int i = 0; i < 16; ++i) a[i] = silu_f(a[i]);
}

DEVINL void d2b(const f32x16& d, int lane, int q, float* wA, float* wB) {
    float pk[8];
#pragma unroll
    for (int a2 = 0; a2 < 4; ++a2) {
        pk[a2 * 2 + 0] = pkh(d[4 * a2 + 0], d[4 * a2 + 1]);
        pk[a2 * 2 + 1] = pkh(d[4 * a2 + 2], d[4 * a2 + 3]);
    }
#pragma unroll
    for (int t = 0; t < 2; ++t) {
        float k0 = q ? pk[(2 * t + 1) * 2 + 0] : pk[(2 * t) * 2 + 0];
        float k1 = q ? pk[(2 * t + 1) * 2 + 1] : pk[(2 * t) * 2 + 1];
        float s0 = q ? pk[(2 * t) * 2 + 0] : pk[(2 * t + 1) * 2 + 0];
        float s1 = q ? pk[(2 * t) * 2 + 1] : pk[(2 * t + 1) * 2 + 1];
        float r0 = __shfl(s0, lane ^ 32, 64);
        float r1 = __shfl(s1, lane ^ 32, 64);
        float* w = t ? wB : wA;
        w[0] = q ? r0 : k0;
        w[1] = q ? r1 : k1;
        w[2] = q ? k0 : r0;
        w[3] = q ? k1 : r1;
    }
}

// ---- chunk stage helpers (128 threads cooperatively move one mtile) ----
DEVINL void ld5(const f32x4* src, f32x4* st, int tid) {
#pragma unroll
    for (int k = 0; k < 5; ++k) st[k] = ld_f4(src + k * 128 + tid);
}
DEVINL void ld4(const f32x4* src, f32x4* st, int tid) {
#pragma unroll
    for (int k = 0; k < 4; ++k) st[k] = ld_f4(src + k * 128 + tid);
}
DEVINL void wr5(f32x4* dst, const f32x4* st, int tid) {
#pragma unroll
    for (int k = 0; k < 5; ++k) dst[k * 128 + tid] = st[k];
}
DEVINL void wr4(f32x4* dst, const f32x4* st, int tid) {
#pragma unroll
    for (int k = 0; k < 4; ++k) dst[k * 128 + tid] = st[k];
}

// =====================================================================
__global__ __launch_bounds__(256) void k_zero(float* __restrict__ p, int n) {
    int i = blockIdx.x * 256 + threadIdx.x;
    if (i < n) p[i] = 0.f;
}

// =====================================================================
struct PackArgs {
    const float* src[14];
    half_t* dst[14];
    int K[14];
    int N[14];
};

__global__ __launch_bounds__(256) void k_pack(PackArgs pa) {
    int mi = blockIdx.y;
    int K = pa.K[mi], N = pa.N[mi];
    int Npad = (N + 31) & ~31;
    int KB = K >> 3;
    int cells = KB * Npad;
    int cell = blockIdx.x * 256 + threadIdx.x;
    if (cell >= cells) return;
    int nn = cell & 31, r2 = cell >> 5;
    int kblk = r2 % KB, ntile = r2 / KB;
    int n = ntile * 32 + nn;
    const float* W = pa.src[mi];
    half8 v;
#pragma unroll
    for (int j = 0; j < 8; ++j) {
        int k = kblk * 8 + j;
        v[j] = (half_t)((n < N) ? W[k * N + n] : 0.f);
    }
    *reinterpret_cast<half8*>(pa.dst[mi] + (size_t)cell * 8) = v;
}

// =====================================================================
// Counting sort of edges by center node: hist -> scan -> bucket.
// =====================================================================
__global__ __launch_bounds__(256) void k_hist(const int* __restrict__ eidx,
                                              int* __restrict__ cnt, int E) {
    int e = blockIdx.x * 256 + threadIdx.x;
    if (e < E) atomicAdd(&cnt[eidx[e]], 1);
}

__global__ __launch_bounds__(1024) void k_scan(const int* __restrict__ cnt,
                                               int* __restrict__ start,
                                               int* __restrict__ cursor, int Nn) {
    __shared__ int sh[1024];
    const int t = threadIdx.x;
    const int C = 5;  // 5120 >= Nn
    int base = t * C;
    int local[C];
    int s = 0;
#pragma unroll
    for (int j = 0; j < C; ++j) {
        int idx = base + j;
        int v = (idx < Nn) ? cnt[idx] : 0;
        local[j] = v;
        s += v;
    }
    sh[t] = s;
    __syncthreads();
    for (int off = 1; off < 1024; off <<= 1) {
        int v = (t >= off) ? sh[t - off] : 0;
        __syncthreads();
        sh[t] += v;
        __syncthreads();
    }
    int run = sh[t] - s;  // exclusive prefix
#pragma unroll
    for (int j = 0; j < C; ++j) {
        int idx = base + j;
        if (idx < Nn) {
            start[idx] = run;
            cursor[idx] = run;
            run += local[j];
        }
    }
    if (t == 1023) start[Nn] = sh[1023];
}

__global__ __launch_bounds__(256) void k_bucket(const int* __restrict__ eidx,
                                                int* __restrict__ cursor,
                                                int* __restrict__ eord, int E) {
    int e = blockIdx.x * 256 + threadIdx.x;
    if (e < E) {
        int pos = atomicAdd(&cursor[eidx[e]], 1);
        eord[pos] = e;
    }
}

// =====================================================================
// K1: front v2 — 2 waves/block (groups 2b,2b+1) share a double-buffered
// LDS weight stage streaming w2b2[0..3] -> e0w1[0..3] -> e0w2[0..1]
// (chunk idx i in Wbuf[i&1]); w2b1 (1KB) stays direct.
// Env contributions -> DENSE contrib[e][64] (no atomics).
// =====================================================================
__global__ __launch_bounds__(128, 2) void k_edge_front(
    const float* __restrict__ g_ea, const float* __restrict__ g_na,
    const float* __restrict__ g_emb, const float* __restrict__ g_eu,
    const int* __restrict__ g_eidx,
    const half_t* __restrict__ b_w2b1, const half_t* __restrict__ b_w2b2,
    const half_t* __restrict__ b_e0w1, const half_t* __restrict__ b_e0w2,
    half_t* __restrict__ g_lat0, float* __restrict__ g_fs, float* __restrict__ g_fv,
    float* __restrict__ contrib, int E) {
    __shared__ f32x4 Wbuf[2][512];  // 2 x 8KB
    const int tid = threadIdx.x;
    const int lane = tid & 63, nl = lane & 31, q = lane >> 5;
    const int wid = tid >> 6;
    const int g = blockIdx.x * 2 + wid;
    const int e = g * 32 + nl;
    float4 ea = *reinterpret_cast<const float4*>(g_ea + e * 4);
    float cut = poly_cut(g_eu[e]);

    const f32x4* s_w2b2 = reinterpret_cast<const f32x4*>(b_w2b2);  // 4 x 512
    const f32x4* s_e0w1 = reinterpret_cast<const f32x4*>(b_e0w1);  // 4 x 512
    const f32x4* s_e0w2 = reinterpret_cast<const f32x4*>(b_e0w2);  // 2 x 512

    f32x4 st[4];
    ld4(s_w2b2, st, tid);  // chunk 0 in flight, hidden under gather + w2b1

    float xw[4];
    if (q == 0) {
        int ce0 = g_eidx[e];
        int ne = g_eidx[E + e];
        float4 nc = *reinterpret_cast<const float4*>(g_na + ce0 * 4);
        float4 nn = *reinterpret_cast<const float4*>(g_na + ne * 4);
        xw[0] = pkh(nc.x, nc.y); xw[1] = pkh(nc.z, nc.w);
        xw[2] = pkh(nn.x, nn.y); xw[3] = pkh(nn.z, nn.w);
    } else {
        f32x4 m0 = ntl_f4(g_emb + e * 8);
        f32x4 m1 = ntl_f4(g_emb + e * 8 + 4);
        xw[0] = pkh(m0[0], m0[1]); xw[1] = pkh(m0[2], m0[3]);
        xw[2] = pkh(m1[0], m1[1]); xw[3] = pkh(m1[2], m1[3]);
    }

    float hB[32], lB[32];
#pragma unroll
    for (int c = 0; c < 4; ++c) {  // w2b1: K=16, direct (tiny)
        f32x16 d = colstage<2>(b_w2b1, xw, c, nl, q);
        silu16(d);
        d2b(d, lane, q, &hB[8 * c], &hB[8 * c + 4]);
    }

    wr4(&Wbuf[0][0], st, tid);
    __syncthreads();  // publishes chunk 0

    half_t* gl = g_lat0 + (size_t)g * 4096;
    // stage A: w2b2 (KB=16), chunks idx 0..3 -> lat = cut*D
#pragma unroll
    for (int c = 0; c < 4; ++c) {
        if (c < 3) ld4(s_w2b2 + (size_t)(c + 1) * 512, st, tid);
        else       ld4(s_e0w1, st, tid);  // bridge -> e0w1 chunk 0 (idx 4)
        f32x16 d = colstage_lds<16>(
            reinterpret_cast<const half_t*>(&Wbuf[c & 1][0]), hB, nl, q);
#pragma unroll
        for (int i = 0; i < 16; ++i) d[i] *= cut;
        d2b(d, lane, q, &lB[8 * c], &lB[8 * c + 4]);
        st_h8(mk8(&lB[8 * c]), gl + ((4 * c + q) * 32 + nl) * 8);
        st_h8(mk8(&lB[8 * c + 4]), gl + ((4 * c + 2 + q) * 32 + nl) * 8);
        __builtin_amdgcn_sched_barrier(0);
        wr4(&Wbuf[(c + 1) & 1][0], st, tid);
        __syncthreads();
    }
    // stage B: e0w1 (KB=16), chunks idx 4..7 (parity == c&1)
#pragma unroll
    for (int c = 0; c < 4; ++c) {
        if (c < 3) ld4(s_e0w1 + (size_t)(c + 1) * 512, st, tid);
        else       ld4(s_e0w2, st, tid);  // bridge -> e0w2 chunk 0 (idx 8)
        f32x16 d = colstage_lds<16>(
            reinterpret_cast<const half_t*>(&Wbuf[c & 1][0]), lB, nl, q);
        silu16(d);
        d2b(d, lane, q, &hB[8 * c], &hB[8 * c + 4]);
        __builtin_amdgcn_sched_barrier(0);
        wr4(&Wbuf[(c + 1) & 1][0], st, tid);
        __syncthreads();
    }
    // stage C: e0w2 chunks idx 8 (parity 0), 9 (parity 1)
    f32x16 d0, d1;
    {
        ld4(s_e0w2 + 512, st, tid);  // chunk idx 9
        d0 = colstage_lds<16>(
            reinterpret_cast<const half_t*>(&Wbuf[0][0]), hB, nl, q);
        __builtin_amdgcn_sched_barrier(0);
        wr4(&Wbuf[1][0], st, tid);
        __syncthreads();
        d1 = colstage_lds<16>(
            reinterpret_cast<const half_t*>(&Wbuf[1][0]), hB, nl, q);
    }
    {
        float* cp = contrib + (size_t)e * 64;
#pragma unroll
        for (int r = 0; r < 16; ++r) {
            int f = (r & 3) + 8 * (r >> 2) + 4 * q;
            int u = f >> 1;
            float v0 = d0[r], v1 = d1[r];
            if ((f & 1) == 0) {
                g_fs[e * 16 + u] = v0 * ea.x;
                cp[u] = v1 * ea.x;
            } else {
                g_fv[e * 48 + u * 3 + 0] = v0 * ea.y;
                g_fv[e * 48 + u * 3 + 1] = v0 * ea.z;
                g_fv[e * 48 + u * 3 + 2] = v0 * ea.w;
                cp[16 + u * 3 + 0] = v1 * ea.y;
                cp[16 + u * 3 + 1] = v1 * ea.z;
                cp[16 + u * 3 + 2] = v1 * ea.w;
            }
        }
    }
}

// =====================================================================
// K2: per-node env aggregation + linear. 64 threads per node (1 wave
// sub-group); coalesced 256B contrib reads via shfl-broadcast indices.
// =====================================================================
__global__ __launch_bounds__(256) void k_node_agg(
    const int* __restrict__ start, const int* __restrict__ eord,
    const float* __restrict__ contrib, const float* __restrict__ wls,
    const float* __restrict__ wlv, float* __restrict__ ls,
    float* __restrict__ lv, int Nn) {
    __shared__ float rawsh[4][64];
    const int t = threadIdx.x & 63;
    const int sub = threadIdx.x >> 6;
    const int n = blockIdx.x * 4 + sub;
    float acc = 0.f;
    if (n < Nn) {
        int s = start[n], en = start[n + 1];
        for (int base = s; base < en; base += 64) {
            int m = en - base; if (m > 64) m = 64;
            int myord = (base + t < en) ? eord[base + t] : 0;
            for (int i = 0; i < m; ++i) {
                int e2 = __shfl(myord, i, 64);
                acc += contrib[(size_t)e2 * 64 + t];
            }
        }
    }
    rawsh[sub][t] = acc;
    __syncthreads();
    if (n < Nn) {
        const float* raws = rawsh[sub];
        if (t < 16) {
            float as = 0.f;
#pragma unroll
            for (int u = 0; u < 16; ++u) as = fmaf(raws[u], wls[u * 16 + t], as);
            ls[n * 16 + t] = as * SC_ENV;
        } else {
            int idx = t - 16;
            int v = idx / 3, c = idx - 3 * v;
            float a = 0.f;
#pragma unroll
            for (int u = 0; u < 16; ++u)
                a = fmaf(raws[16 + u * 3 + c], wlv[u * 16 + v], a);
            lv[n * 48 + v * 3 + c] = a * SC_ENV;
        }
    }
}

// =====================================================================
// K3: FUSED layer0 (fold role + lat role in one launch, round-11 proven).
// =====================================================================
__global__ __launch_bounds__(128, 2) void k_foldlat(
    const float* __restrict__ g_ea, const float* __restrict__ g_eu,
    const int* __restrict__ g_eidx,
    const float* __restrict__ g_fs, const float* __restrict__ g_fv,
    float* __restrict__ gfs2, float* __restrict__ gfv2,
    const float* __restrict__ ls0, const float* __restrict__ lv0,
    const half_t* __restrict__ b_lat1w1, const half_t* __restrict__ b_lat1w2,
    const half_t* __restrict__ b_e1w1, const half_t* __restrict__ b_e1w2,
    const half_t* __restrict__ b_gw1, const half_t* __restrict__ b_gw2,
    const half_t* __restrict__ g_lat0, half_t* __restrict__ g_lat1,
    float* __restrict__ contrib, int nblk2, int E) {
    __shared__ __align__(16) char smem[39424];
    const int tid = threadIdx.x;
    const int lane = tid & 63, nl = lane & 31, q = lane >> 5;
    const int wid = tid >> 6;
    const int bid = blockIdx.x;

    if (bid < nblk2) {
        // ============================ FOLD ============================
        half_t* sS = reinterpret_cast<half_t*>(smem) + wid * (32 * SSD);
        half_t* Vsh = reinterpret_cast<half_t*>(smem + 4352) + wid * (32 * VPH);
        f32x4* Wb0 = reinterpret_cast<f32x4*>(smem + 23040);
        f32x4* Wb1 = Wb0 + 512;
        const int g = bid * 2 + wid;
        const int e = g * 32 + nl;
        int ce = g_eidx[e];

        const f32x4* gsrc = reinterpret_cast<const f32x4*>(b_gw2);
        f32x4 st[4];
#pragma unroll
        for (int k = 0; k < 4; ++k) st[k] = ld_f4(gsrc + k * 128 + tid);

#pragma unroll
        for (int mm = 0; mm < 8; ++mm) {
            int m = q * 8 + mm;
            float fs = ntl_f(g_fs + e * 16 + m);
            float fv0 = ntl_f(g_fv + e * 48 + m * 3 + 0);
            float fv1 = ntl_f(g_fv + e * 48 + m * 3 + 1);
            float fv2 = ntl_f(g_fv + e * 48 + m * 3 + 2);
            float es = ls0[ce * 16 + m];
            float ev0 = lv0[ce * 48 + m * 3 + 0];
            float ev1 = lv0[ce * 48 + m * 3 + 1];
            float ev2 = lv0[ce * 48 + m * 3 + 2];
            sS[nl * SSD + 2 * m + 0] = (half_t)(fs * es);
            sS[nl * SSD + 2 * m + 1] =
                (half_t)((fv0 * ev0 + fv1 * ev1 + fv2 * ev2) * INV_S3);
            half_t* vp = Vsh + nl * VPH;
            vp[m * 3 + 0] = (half_t)(fs * ev0);
            vp[m * 3 + 1] = (half_t)(fs * ev1);
            vp[m * 3 + 2] = (half_t)(fs * ev2);
            vp[(16 + m) * 3 + 0] = (half_t)(fv0 * es);
            vp[(16 + m) * 3 + 1] = (half_t)(fv1 * es);
            vp[(16 + m) * 3 + 2] = (half_t)(fv2 * es);
            vp[(32 + m) * 3 + 0] = (half_t)((fv1 * ev2 - fv2 * ev1) * INV_S2);
            vp[(32 + m) * 3 + 1] = (half_t)((fv2 * ev0 - fv0 * ev2) * INV_S2);
            vp[(32 + m) * 3 + 2] = (half_t)((fv0 * ev1 - fv1 * ev0) * INV_S2);
        }

        float lB[40];
        const half_t* gl0 = g_lat0 + (size_t)g * 4096;
#pragma unroll
        for (int h = 0; h < 8; ++h) {
            f32x4 v = ntl_f4(gl0 + ((2 * h + q) * 32 + nl) * 8);
            lB[h * 4 + 0] = v[0]; lB[h * 4 + 1] = v[1];
            lB[h * 4 + 2] = v[2]; lB[h * 4 + 3] = v[3];
        }
        __syncthreads();

#pragma unroll
        for (int j2 = 0; j2 < 4; ++j2) {
            lB[32 + j2] = ld_pk2(sS + nl * SSD + 8 * q + 2 * j2);
            lB[36 + j2] = ld_pk2(sS + nl * SSD + 16 + 8 * q + 2 * j2);
        }

        float hB[32];
#pragma unroll
        for (int c = 0; c < 4; ++c) {  // gw1 direct (hides stage-0 latency)
            f32x16 d = colstage<20>(b_gw1, lB, c, nl, q);
            silu16(d);
            d2b(d, lane, q, &hB[8 * c], &hB[8 * c + 4]);
        }

#pragma unroll
        for (int k = 0; k < 4; ++k) Wb0[k * 128 + tid] = st[k];
        __syncthreads();

        float fsacc[8];
        float fvacc[8][3];
#pragma unroll
        for (int s = 0; s < 8; ++s) {
            fsacc[s] = 0.f;
            fvacc[s][0] = fvacc[s][1] = fvacc[s][2] = 0.f;
        }

        for (int c = 0; c < 40; ++c) {
            const int buf = c & 1;
            f32x4* cur = buf ? Wb1 : Wb0;
            f32x4* nxt = buf ? Wb0 : Wb1;
            if (c + 1 < 40) {
#pragma unroll
                for (int k = 0; k < 4; ++k)
                    st[k] = ld_f4(gsrc + (size_t)(c + 1) * 512 + k * 128 + tid);
            }
            f32x16 d;
            {
                WFrag f;
                const half_t* wp = reinterpret_cast<const half_t*>(cur);
#pragma unroll
                for (int h = 0; h < 8; ++h)
                    f.a[h] = *reinterpret_cast<const half8*>(
                        wp + ((q + 2 * h) * 32 + nl) * 8);
                d = mfma8w(f, hB);
            }
            if (c < 16) {
                int pu0 = 2 * c, pu1 = pu0 + 1;
                float S0 = (float)sS[nl * SSD + 2 * (pu0 & 15) + (pu0 >> 4)];
                float S1 = (float)sS[nl * SSD + 2 * (pu1 & 15) + (pu1 >> 4)];
#pragma unroll
                for (int r = 0; r < 16; ++r) {
                    int a = r >> 2, bb = r & 3, slot = (a & 1) * 4 + bb;
                    fsacc[slot] = fmaf((a < 2) ? S0 : S1, d[r], fsacc[slot]);
                }
            } else {
                int w0i = 2 * c - 32, w1i = w0i + 1;
                const half_t* vp = Vsh + nl * VPH;
                float V00 = (float)vp[w0i * 3], V01 = (float)vp[w0i * 3 + 1], V02 = (float)vp[w0i * 3 + 2];
                float V10 = (float)vp[w1i * 3], V11 = (float)vp[w1i * 3 + 1], V12 = (float)vp[w1i * 3 + 2];
#pragma unroll
                for (int r = 0; r < 16; ++r) {
                    int a = r >> 2, bb = r & 3, slot = (a & 1) * 4 + bb;
                    float x0 = (a < 2) ? V00 : V10;
                    float x1 = (a < 2) ? V01 : V11;
                    float x2 = (a < 2) ? V02 : V12;
                    fvacc[slot][0] = fmaf(x0, d[r], fvacc[slot][0]);
                    fvacc[slot][1] = fmaf(x1, d[r], fvacc[slot][1]);
                    fvacc[slot][2] = fmaf(x2, d[r], fvacc[slot][2]);
                }
            }
            __builtin_amdgcn_sched_barrier(0);
            if (c + 1 < 40) {
#pragma unroll
                for (int k = 0; k < 4; ++k) nxt[k * 128 + tid] = st[k];
            }
            __syncthreads();
        }

        {
            float* fp = gfs2 + e * 16 + 4 * q;
            f32x4 flo = {fsacc[0] * SC_FS, fsacc[1] * SC_FS,
                         fsacc[2] * SC_FS, fsacc[3] * SC_FS};
            f32x4 fhi = {fsacc[4] * SC_FS, fsacc[5] * SC_FS,
                         fsacc[6] * SC_FS, fsacc[7] * SC_FS};
            st_f4(flo, fp);
            st_f4(fhi, fp + 8);
            float t2[24];
#pragma unroll
            for (int s = 0; s < 4; ++s) {
#pragma unroll
                for (int c3 = 0; c3 < 3; ++c3) {
                    t2[s * 3 + c3] = fvacc[s][c3] * SC_FV;
                    t2[12 + s * 3 + c3] = fvacc[4 + s][c3] * SC_FV;
                }
            }
            float* vlo = gfv2 + e * 48 + 12 * q;
            float* vhi = gfv2 + e * 48 + 24 + 12 * q;
#pragma unroll
            for (int i = 0; i < 3; ++i) {
                f32x4 a = {t2[4 * i + 0], t2[4 * i + 1], t2[4 * i + 2], t2[4 * i + 3]};
                f32x4 b = {t2[12 + 4 * i + 0], t2[12 + 4 * i + 1],
                           t2[12 + 4 * i + 2], t2[12 + 4 * i + 3]};
                st_f4(a, vlo + 4 * i);
                st_f4(b, vhi + 4 * i);
            }
        }
    } else {
        // ============================ LAT =============================
        half_t* sS = reinterpret_cast<half_t*>(smem) + wid * (32 * SSD);
        f32x4* Wb0 = reinterpret_cast<f32x4*>(smem + 4352);
        f32x4* Wb1 = Wb0 + 640;
        const int b = bid - nblk2;
        const int g = b * 2 + wid;
        const int e = g * 32 + nl;
        int ce = g_eidx[e];

        const f32x4* w11 = reinterpret_cast<const f32x4*>(b_lat1w1);  // 4 x 640
        const f32x4* w12 = reinterpret_cast<const f32x4*>(b_lat1w2);  // 4 x 512
        const f32x4* w21 = reinterpret_cast<const f32x4*>(b_e1w1);    // 4 x 512
        const f32x4* w22 = reinterpret_cast<const f32x4*>(b_e1w2);    // 1 x 512

        f32x4 st[5];
        ld5(w11, st, tid);  // chunk 0 in flight

#pragma unroll
        for (int mm = 0; mm < 8; ++mm) {
            int m = q * 8 + mm;
            float fs = ntl_f(g_fs + e * 16 + m);
            float fv0 = ntl_f(g_fv + e * 48 + m * 3 + 0);
            float fv1 = ntl_f(g_fv + e * 48 + m * 3 + 1);
            float fv2 = ntl_f(g_fv + e * 48 + m * 3 + 2);
            float es = ls0[ce * 16 + m];
            float ev0 = lv0[ce * 48 + m * 3 + 0];
            float ev1 = lv0[ce * 48 + m * 3 + 1];
            float ev2 = lv0[ce * 48 + m * 3 + 2];
            sS[nl * SSD + 2 * m + 0] = (half_t)(fs * es);
            sS[nl * SSD + 2 * m + 1] =
                (half_t)((fv0 * ev0 + fv1 * ev1 + fv2 * ev2) * INV_S3);
        }

        float lB[40];
        const half_t* gl0 = g_lat0 + (size_t)g * 4096;
#pragma unroll
        for (int h = 0; h < 8; ++h) {
            f32x4 v = ntl_f4(gl0 + ((2 * h + q) * 32 + nl) * 8);
            lB[h * 4 + 0] = v[0]; lB[h * 4 + 1] = v[1];
            lB[h * 4 + 2] = v[2]; lB[h * 4 + 3] = v[3];
        }
        float4 ea = *reinterpret_cast<const float4*>(g_ea + e * 4);
        float cut = poly_cut(g_eu[e]);

        wr5(Wb0, st, tid);
        __syncthreads();  // publishes chunk 0

#pragma unroll
        for (int j2 = 0; j2 < 4; ++j2) {
            lB[32 + j2] = ld_pk2(sS + nl * SSD + 8 * q + 2 * j2);
            lB[36 + j2] = ld_pk2(sS + nl * SSD + 16 + 8 * q + 2 * j2);
        }

        float hB[32];
        // stage A: lat1w1 (KB=20), chunks idx 0..3
#pragma unroll
        for (int c = 0; c < 4; ++c) {
            if (c < 3) ld5(w11 + (size_t)(c + 1) * 640, st, tid);
            else       ld4(w12, st, tid);  // bridge -> lat1w2 (idx 4)
            f32x16 d = colstage_lds<20>(
                reinterpret_cast<const half_t*>((c & 1) ? Wb1 : Wb0), lB, nl, q);
            silu16(d);
            d2b(d, lane, q, &hB[8 * c], &hB[8 * c + 4]);
            __builtin_amdgcn_sched_barrier(0);
            if (c < 3) wr5(((c + 1) & 1) ? Wb1 : Wb0, st, tid);
            else       wr4(((c + 1) & 1) ? Wb1 : Wb0, st, tid);
            __syncthreads();
        }
        // stage B: lat1w2 (KB=16), chunks idx 4..7 (parity == c&1)
        half_t* gl1 = g_lat1 + (size_t)g * 4096;
        float sc = A_COLD * cut;
#pragma unroll
        for (int c = 0; c < 4; ++c) {
            if (c < 3) ld4(w12 + (size_t)(c + 1) * 512, st, tid);
            else       ld4(w21, st, tid);  // bridge -> e1w1 (idx 8)
            f32x16 d = colstage_lds<16>(
                reinterpret_cast<const half_t*>((c & 1) ? Wb1 : Wb0), hB, nl, q);
#pragma unroll
            for (int i = 0; i < 16; ++i) d[i] *= sc;
            float nw[8];
            d2b(d, lane, q, nw, nw + 4);
#pragma unroll
            for (int p = 0; p < 8; ++p) {
                float2 o = uph(lB[8 * c + p]);
                float2 nn2 = uph(nw[p]);
                lB[8 * c + p] = pkh(C_OLD * o.x + nn2.x, C_OLD * o.y + nn2.y);
            }
            st_h8(mk8(&lB[8 * c]), gl1 + ((4 * c + q) * 32 + nl) * 8);
            st_h8(mk8(&lB[8 * c + 4]), gl1 + ((4 * c + 2 + q) * 32 + nl) * 8);
            __builtin_amdgcn_sched_barrier(0);
            wr4(((c + 1) & 1) ? Wb1 : Wb0, st, tid);
            __syncthreads();
        }
        // stage C: e1w1 (KB=16), chunks idx 8..11 (parity == c&1)
#pragma unroll
        for (int c = 0; c < 4; ++c) {
            if (c == 3) ld4(w22, st, tid);  // bridge -> e1w2 (idx 12)
            f32x16 d = colstage_lds<16>(
                reinterpret_cast<const half_t*>((c & 1) ? Wb1 : Wb0), lB, nl, q);
            silu16(d);
            d2b(d, lane, q, &hB[8 * c], &hB[8 * c + 4]);
            if (c < 3) ld4(w21 + (size_t)(c + 1) * 512, st, tid);
            __builtin_amdgcn_sched_barrier(0);
            wr4(((c + 1) & 1) ? Wb1 : Wb0, st, tid);
            __syncthreads();
        }
        // stage D: e1w2 (idx 12, parity 0) -> dense contrib (no atomics)
        {
            f32x16 d = colstage_lds<16>(
                reinterpret_cast<const half_t*>(Wb0), hB, nl, q);
            float* cp = contrib + (size_t)e * 64;
#pragma unroll
            for (int r = 0; r < 16; ++r) {
                int f = (r & 3) + 8 * (r >> 2) + 4 * q;
                int u = f >> 1;
                float val = d[r];
                if ((f & 1) == 0) {
                    cp[u] = val * ea.x;
                } else {
                    cp[16 + u * 3 + 0] = val * ea.y;
                    cp[16 + u * 3 + 1] = val * ea.z;
                    cp[16 + u * 3 + 2] = val * ea.w;
                }
            }
        }
    }
}

// =====================================================================
// K5: layer1 v2 — staged weight stream (unchanged from round 11).
// =====================================================================
__global__ __launch_bounds__(128, 2) void k_layer1(
    const int* __restrict__ g_eidx, const float* __restrict__ gfs2,
    const float* __restrict__ gfv2, const float* __restrict__ ls1,
    const float* __restrict__ lv1,
    const half_t* __restrict__ b_flw1, const half_t* __restrict__ b_flw2,
    const half_t* __restrict__ b_gw1, const half_t* __restrict__ b_gw2,
    const half_t* __restrict__ g_lat1, float* __restrict__ g_out, int E) {
    __shared__ half_t sS2[2][32 * SSD];
    __shared__ half_t Vsh2[2][32 * VPH];
    __shared__ f32x4 Wbuf[2][640];
    const int tid = threadIdx.x;
    const int lane = tid & 63, nl = lane & 31, q = lane >> 5;
    const int wid = tid >> 6;
    const int g = blockIdx.x * 2 + wid;
    const int e = g * 32 + nl;
    int ce = g_eidx[e];
    half_t* sS = sS2[wid];
    half_t* Vsh = Vsh2[wid];

    const f32x4* wf1 = reinterpret_cast<const f32x4*>(b_flw1);
    const f32x4* wf2 = reinterpret_cast<const f32x4*>(b_flw2);
    const f32x4* wg1 = reinterpret_cast<const f32x4*>(b_gw1);
    const f32x4* wg2 = reinterpret_cast<const f32x4*>(b_gw2);

    f32x4 st[5];
    ld5(wf1, st, tid);

#pragma unroll
    for (int mm = 0; mm < 8; ++mm) {
        int m = q * 8 + mm;
        float fs = ntl_f(gfs2 + e * 16 + m);
        float fv0 = ntl_f(gfv2 + e * 48 + m * 3 + 0);
        float fv1 = ntl_f(gfv2 + e * 48 + m * 3 + 1);
        float fv2 = ntl_f(gfv2 + e * 48 + m * 3 + 2);
        float es = ls1[ce * 16 + m];
        float ev0 = lv1[ce * 48 + m * 3 + 0];
        float ev1 = lv1[ce * 48 + m * 3 + 1];
        float ev2 = lv1[ce * 48 + m * 3 + 2];
        sS[nl * SSD + 2 * m + 0] = (half_t)(fs * es);
        sS[nl * SSD + 2 * m + 1] =
            (half_t)((fv0 * ev0 + fv1 * ev1 + fv2 * ev2) * INV_S3);
        half_t* vp = Vsh + nl * VPH;
        vp[m * 3 + 0] = (half_t)(fs * ev0);
        vp[m * 3 + 1] = (half_t)(fs * ev1);
        vp[m * 3 + 2] = (half_t)(fs * ev2);
        vp[(16 + m) * 3 + 0] = (half_t)(fv0 * es);
        vp[(16 + m) * 3 + 1] = (half_t)(fv1 * es);
        vp[(16 + m) * 3 + 2] = (half_t)(fv2 * es);
        vp[(32 + m) * 3 + 0] = (half_t)((fv1 * ev2 - fv2 * ev1) * INV_S2);
        vp[(32 + m) * 3 + 1] = (half_t)((fv2 * ev0 - fv0 * ev2) * INV_S2);
        vp[(32 + m) * 3 + 2] = (half_t)((fv0 * ev1 - fv1 * ev0) * INV_S2);
    }

    float lB[40];
    const half_t* gl1 = g_lat1 + (size_t)g * 4096;
#pragma unroll
    for (int h = 0; h < 8; ++h) {
        f32x4 v = ntl_f4(gl1 + ((2 * h + q) * 32 + nl) * 8);
        lB[h * 4 + 0] = v[0]; lB[h * 4 + 1] = v[1];
        lB[h * 4 + 2] = v[2]; lB[h * 4 + 3] = v[3];
    }

    wr5(&Wbuf[0][0], st, tid);
    __syncthreads();

#pragma unroll
    for (int j2 = 0; j2 < 4; ++j2) {
        lB[32 + j2] = ld_pk2(sS + nl * SSD + 8 * q + 2 * j2);
        lB[36 + j2] = ld_pk2(sS + nl * SSD + 16 + 8 * q + 2 * j2);
    }

    float hB[32];
#pragma unroll
    for (int c = 0; c < 4; ++c) {  // flw1, chunks 0..3
        if (c < 3) ld5(wf1 + (size_t)(c + 1) * 640, st, tid);
        else       ld4(wf2, st, tid);
        f32x16 d = colstage_lds<20>(
            reinterpret_cast<const half_t*>(&Wbuf[c & 1][0]), lB, nl, q);
        silu16(d);
        d2b(d, lane, q, &hB[8 * c], &hB[8 * c + 4]);
        __builtin_amdgcn_sched_barrier(0);
        if (c < 3) wr5(&Wbuf[(c + 1) & 1][0], st, tid);
        else       wr4(&Wbuf[(c + 1) & 1][0], st, tid);
        __syncthreads();
    }
    float fw[8];
    {  // flw2 (idx 4, parity 0)
        ld5(wg1, st, tid);
        f32x16 d = colstage_lds<16>(
            reinterpret_cast<const half_t*>(&Wbuf[0][0]), hB, nl, q);
#pragma unroll
        for (int r = 0; r < 8; ++r) fw[r] = d[r];
        __builtin_amdgcn_sched_barrier(0);
        wr5(&Wbuf[1][0], st, tid);
        __syncthreads();
    }
#pragma unroll
    for (int c = 0; c < 4; ++c) {  // gw1, chunks idx 5..8
        if (c < 3) ld5(wg1 + (size_t)(c + 1) * 640, st, tid);
        else       ld4(wg2 + (size_t)16 * 512, st, tid);
        f32x16 d = colstage_lds<20>(
            reinterpret_cast<const half_t*>(&Wbuf[(c + 1) & 1][0]), lB, nl, q);
        silu16(d);
        d2b(d, lane, q, &hB[8 * c], &hB[8 * c + 4]);
        __builtin_amdgcn_sched_barrier(0);
        if (c < 3) wr5(&Wbuf[c & 1][0], st, tid);
        else       wr4(&Wbuf[c & 1][0], st, tid);
        __syncthreads();
    }
    float fvacc[8][3];
#pragma unroll
    for (int s = 0; s < 8; ++s) fvacc[s][0] = fvacc[s][1] = fvacc[s][2] = 0.f;
    for (int j = 0; j < 24; ++j) {  // gw2 fold, mtiles 16..39
        const int pb = (j + 1) & 1;
        if (j < 23) {
#pragma unroll
            for (int k = 0; k < 4; ++k)
                st[k] = ld_f4(wg2 + (size_t)(17 + j) * 512 + k * 128 + tid);
        }
        f32x16 d;
        {
            WFrag f;
            const half_t* wp = reinterpret_cast<const half_t*>(&Wbuf[pb][0]);
#pragma unroll
            for (int h = 0; h < 8; ++h)
                f.a[h] = *reinterpret_cast<const half8*>(
                    wp + ((q + 2 * h) * 32 + nl) * 8);
            d = mfma8w(f, hB);
        }
        {
            int w0i = 2 * j, w1i = 2 * j + 1;
            const half_t* vp = Vsh + nl * VPH;
            float V00 = (float)vp[w0i * 3], V01 = (float)vp[w0i * 3 + 1], V02 = (float)vp[w0i * 3 + 2];
            float V10 = (float)vp[w1i * 3], V11 = (float)vp[w1i * 3 + 1], V12 = (float)vp[w1i * 3 + 2];
#pragma unroll
            for (int r = 0; r < 16; ++r) {
                int a = r >> 2, bb = r & 3, slot = (a & 1) * 4 + bb;
                float x0 = (a < 2) ? V00 : V10;
                float x1 = (a < 2) ? V01 : V11;
                float x2 = (a < 2) ? V02 : V12;
                fvacc[slot][0] = fmaf(x0, d[r], fvacc[slot][0]);
                fvacc[slot][1] = fmaf(x1, d[r], fvacc[slot][1]);
                fvacc[slot][2] = fmaf(x2, d[r], fvacc[slot][2]);
            }
        }
        __builtin_amdgcn_sched_barrier(0);
        if (j < 23) wr4(&Wbuf[pb ^ 1][0], st, tid);
        __syncthreads();
    }
    {
        float o0 = 0.f, o1 = 0.f, o2 = 0.f;
#pragma unroll
        for (int s = 0; s < 8; ++s) {
            o0 = fmaf(fw[s], fvacc[s][0], o0);
            o1 = fmaf(fw[s], fvacc[s][1], o1);
            o2 = fmaf(fw[s], fvacc[s][2], o2);
        }
        o0 += __shfl(o0, lane ^ 32, 64);
        o1 += __shfl(o1, lane ^ 32, 64);
        o2 += __shfl(o2, lane ^ 32, 64);
        if (q == 0) {
            g_out[e * 3 + 0] = o0 * SC_OUT;
            g_out[e * 3 + 1] = o1 * SC_OUT;
            g_out[e * 3 + 2] = o2 * SC_OUT;
        }
    }
}

// =====================================================================
extern "C" void kernel_launch(void* const* d_in, const int* in_sizes, int n_in,
                              void* d_out, int out_size, void* d_ws, size_t ws_size,
                              hipStream_t stream) {
    const float* g_ea = (const float*)d_in[0];
    const float* g_na = (const float*)d_in[1];
    const float* g_emb = (const float*)d_in[2];
    const float* g_eu = (const float*)d_in[3];
    const int* g_eidx = (const int*)d_in[4];
    const float* w2b1 = (const float*)d_in[5];
    const float* w2b2 = (const float*)d_in[6];
    const float* lat1w1 = (const float*)d_in[7];
    const float* lat1w2 = (const float*)d_in[8];
    const float* e0w1 = (const float*)d_in[9];
    const float* e0w2 = (const float*)d_in[10];
    const float* e1w1 = (const float*)d_in[11];
    const float* e1w2 = (const float*)d_in[12];
    const float* l2w0w1 = (const float*)d_in[13];
    const float* l2w0w2 = (const float*)d_in[14];
    const float* l2w1w1 = (const float*)d_in[15];
    const float* l2w1w2 = (const float*)d_in[16];
    const float* envws = (const float*)d_in[17];
    const float* envwv = (const float*)d_in[18];
    const float* flw1 = (const float*)d_in[19];
    const float* flw2 = (const float*)d_in[20];
    float* out = (float*)d_out;

    const int E = in_sizes[3];       // 120000
    const int Nn = in_sizes[1] / 4;  // 5000
    const int nblk = E / 32;         // 3750
    const int nblk2 = nblk / 2;      // 1875

    float* p = (float*)d_ws;
    float* gfs = p;  p += (size_t)E * 16;
    float* gfv = p;  p += (size_t)E * 48;
    float* gfs2 = p; p += (size_t)E * 16;
    float* gfv2 = p; p += (size_t)E * 48;
    float* contrib = p; p += (size_t)E * 64;
    float* ls0 = p;  p += (size_t)Nn * 16;
    float* lv0 = p;  p += (size_t)Nn * 48;
    float* ls1 = p;  p += (size_t)Nn * 16;
    float* lv1 = p;  p += (size_t)Nn * 48;
    half_t* hp = (half_t*)p;
    half_t* lat0h = hp; hp += (size_t)nblk * 4096;
    half_t* lat1h = hp; hp += (size_t)nblk * 4096;

    const int KN[14][2] = {{16, 128}, {128, 128}, {128, 128}, {128, 64},
                           {160, 128}, {128, 128}, {128, 128}, {128, 32},
                           {160, 128}, {128, 1280}, {160, 128}, {128, 1280},
                           {160, 128}, {128, 16}};
    const float* srcs[14] = {w2b1, w2b2, e0w1, e0w2, lat1w1, lat1w2, e1w1, e1w2,
                             l2w0w1, l2w0w2, l2w1w1, l2w1w2, flw1, flw2};
    PackArgs pa;
    half_t* bptr[14];
    for (int i = 0; i < 14; ++i) {
        int K = KN[i][0], N = KN[i][1];
        int Npad = (N + 31) & ~31;
        bptr[i] = hp;
        hp += (size_t)K * Npad;
        pa.src[i] = srcs[i];
        pa.dst[i] = bptr[i];
        pa.K[i] = K;
        pa.N[i] = N;
    }
    // int workspace (sorting), after weight packs
    int* ip = (int*)hp;
    int* cnt = ip;    ip += Nn;
    int* cursor = ip; ip += Nn;
    int* startp = ip; ip += Nn + 1;
    int* eord = ip;   ip += E;

    k_pack<<<dim3(80, 14), 256, 0, stream>>>(pa);
    k_zero<<<(Nn + 255) / 256, 256, 0, stream>>>((float*)cnt, Nn);
    k_hist<<<(E + 255) / 256, 256, 0, stream>>>(g_eidx, cnt, E);
    k_scan<<<1, 1024, 0, stream>>>(cnt, startp, cursor, Nn);
    k_bucket<<<(E + 255) / 256, 256, 0, stream>>>(g_eidx, cursor, eord, E);

    k_edge_front<<<nblk2, 128, 0, stream>>>(g_ea, g_na, g_emb, g_eu, g_eidx,
                                            bptr[0], bptr[1], bptr[2], bptr[3],
                                            lat0h, gfs, gfv, contrib, E);
    const int nagg = (Nn + 3) / 4;
    k_node_agg<<<nagg, 256, 0, stream>>>(startp, eord, contrib, envws, envwv,
                                         ls0, lv0, Nn);
    k_foldlat<<<nblk, 128, 0, stream>>>(g_ea, g_eu, g_eidx, gfs, gfv, gfs2, gfv2,
                                        ls0, lv0, bptr[4], bptr[5], bptr[6],
                                        bptr[7], bptr[8], bptr[9], lat0h, lat1h,
                                        contrib, nblk2, E);
    k_node_agg<<<nagg, 256, 0, stream>>>(startp, eord, contrib, envws + 256,
                                         envwv + 256, ls1, lv1, Nn);
    k_layer1<<<nblk2, 128, 0, stream>>>(g_eidx, gfs2, gfv2, ls1, lv1,
                                        bptr[12], bptr[13], bptr[10], bptr[11],
                                        lat1h, out, E);
}